// Round 8
// baseline (661.462 us; speedup 1.0000x reference)
//
#include <hip/hip_runtime.h>
#include <math.h>

#define N_NODES 50000
#define N_EDGES 800000
#define N_GRAPHS 64
#define NREP 32
#define LN_EPS 1e-5f
#define SCAN_BLKS 196          // ceil(50000/256)
#define DBINS 64

typedef __attribute__((ext_vector_type(8))) short bf16x8;
typedef __attribute__((ext_vector_type(4))) float f32x4;
typedef __attribute__((ext_vector_type(2))) _Float16 half2v;

// ---------------- DPP-based reductions (no LDS latency) ----------------
template <int CTRL>
__device__ __forceinline__ float dppadd(float v) {
  int t = __builtin_amdgcn_update_dpp(0, __float_as_int(v), CTRL, 0xF, 0xF, true);
  return v + __int_as_float(t);
}
__device__ __forceinline__ float red16d(float p) {
  p = dppadd<0xB1>(p);   // quad_perm [1,0,3,2]
  p = dppadd<0x4E>(p);   // quad_perm [2,3,0,1]
  p = dppadd<0x141>(p);  // row_half_mirror
  p = dppadd<0x140>(p);  // row_mirror
  return p;
}
__device__ __forceinline__ float red64(float p) {
  p = red16d(p);
  p += __shfl_xor(p, 16); p += __shfl_xor(p, 32);
  return p;
}

__device__ __forceinline__ unsigned f2bf(float f) {  // rne f32->bf16
  unsigned u = __float_as_uint(f);
  return (u + 0x7fffu + ((u >> 16) & 1u)) >> 16;
}
__device__ __forceinline__ float bflo(unsigned u) { return __uint_as_float(u << 16); }
__device__ __forceinline__ float bfhi(unsigned u) { return __uint_as_float(u & 0xffff0000u); }

__device__ __forceinline__ half2v u2h(unsigned u) {
  return __builtin_bit_cast(half2v, u);
}
__device__ __forceinline__ float dot8h(uint4 xh, unsigned w0, unsigned w1,
                                       unsigned w2, unsigned w3) {
#if __has_builtin(__builtin_amdgcn_fdot2)
  float s = __builtin_amdgcn_fdot2(u2h(xh.x), u2h(w0), 0.f, false);
  s = __builtin_amdgcn_fdot2(u2h(xh.y), u2h(w1), s, false);
  s = __builtin_amdgcn_fdot2(u2h(xh.z), u2h(w2), s, false);
  s = __builtin_amdgcn_fdot2(u2h(xh.w), u2h(w3), s, false);
  return s;
#else
  float s = 0.f;
  half2v a;
  a = u2h(xh.x); { half2v b = u2h(w0); s += (float)a.x*(float)b.x + (float)a.y*(float)b.y; }
  a = u2h(xh.y); { half2v b = u2h(w1); s += (float)a.x*(float)b.x + (float)a.y*(float)b.y; }
  a = u2h(xh.z); { half2v b = u2h(w2); s += (float)a.x*(float)b.x + (float)a.y*(float)b.y; }
  a = u2h(xh.w); { half2v b = u2h(w3); s += (float)a.x*(float)b.x + (float)a.y*(float)b.y; }
  return s;
#endif
}

// ---------------- K1: per-dst degree + edge_attr sum ----------------
__global__ void k_hist(const int* __restrict__ dst, const float* __restrict__ ea,
                       int* __restrict__ deg, float* __restrict__ easum) {
  int e = blockIdx.x * 256 + threadIdx.x;
  if (e >= N_EDGES) return;
  int d = dst[e];
  atomicAdd(&deg[d], 1);
  atomicAdd(&easum[d], ea[e]);
}

// ---------------- degree-bucket counting sort (descending degree) ----------------
__global__ void k_dhist(const int* __restrict__ deg, int* __restrict__ dh) {
  int n = blockIdx.x * 256 + threadIdx.x;
  if (n >= N_NODES) return;
  int bin = (DBINS - 1) - min(deg[n], DBINS - 1);   // descending
  atomicAdd(&dh[bin], 1);
}
__global__ void k_dscan(const int* __restrict__ dh, int* __restrict__ dbase) {
  int t = threadIdx.x;                 // 64 threads
  __shared__ int sm[DBINS];
  sm[t] = dh[t]; __syncthreads();
  for (int o = 1; o < DBINS; o <<= 1) {
    int u = (t >= o) ? sm[t - o] : 0;
    __syncthreads();
    sm[t] += u;
    __syncthreads();
  }
  dbase[t] = (t == 0) ? 0 : sm[t - 1];
}
__global__ void k_dscatter(const int* __restrict__ deg, const int* __restrict__ dbase,
                           int* __restrict__ dcur, int* __restrict__ order) {
  int n = blockIdx.x * 256 + threadIdx.x;
  if (n >= N_NODES) return;
  int bin = (DBINS - 1) - min(deg[n], DBINS - 1);
  int pos = dbase[bin] + atomicAdd(&dcur[bin], 1);
  order[pos] = n;
}

// ---------------- K2: multi-block exclusive scan of quad-padded lengths ----------
__global__ void k_scanA(const int* __restrict__ deg, int* __restrict__ part) {
  int t = threadIdx.x;
  int i = blockIdx.x * 256 + t;
  int len = (i < N_NODES) ? ((deg[i] + 4) & ~3) : 0;
  __shared__ int sm[256];
  sm[t] = len; __syncthreads();
  for (int o = 128; o > 0; o >>= 1) {
    if (t < o) sm[t] += sm[t + o];
    __syncthreads();
  }
  if (t == 0) part[blockIdx.x] = sm[0];
}
__global__ void k_scanB(const int* __restrict__ part, int* __restrict__ base) {
  int t = threadIdx.x;                 // 256 threads, 1 block
  __shared__ int sm[256];
  int v = (t < SCAN_BLKS) ? part[t] : 0;
  sm[t] = v; __syncthreads();
  for (int o = 1; o < 256; o <<= 1) {
    int u = (t >= o) ? sm[t - o] : 0;
    __syncthreads();
    sm[t] += u;
    __syncthreads();
  }
  base[t] = (t == 0) ? 0 : sm[t - 1];  // exclusive
}
// scanC fused with self-loop + sentinel-pad writes
__global__ void k_scanC(const int* __restrict__ deg, const int* __restrict__ base,
                        const float* __restrict__ easum,
                        int* __restrict__ off2,
                        int* __restrict__ ssrc, float* __restrict__ sea) {
  int t = threadIdx.x;
  int i = blockIdx.x * 256 + t;
  int d = (i < N_NODES) ? deg[i] : 0;
  int len = (i < N_NODES) ? ((d + 4) & ~3) : 0;
  __shared__ int sm[256];
  sm[t] = len; __syncthreads();
  for (int o = 1; o < 256; o <<= 1) {
    int u = (t >= o) ? sm[t - o] : 0;
    __syncthreads();
    sm[t] += u;
    __syncthreads();
  }
  int incl = sm[t];
  if (i < N_NODES) {
    int b = base[blockIdx.x] + incl - len;
    off2[i] = b;
    // self-loop entry + sentinel pads
    ssrc[b + d] = i;
    sea[b + d]  = easum[i] / fmaxf((float)d, 1.0f);
    for (int j = d + 1; j < len; ++j) { ssrc[b + j] = -1; sea[b + j] = 0.f; }
  }
  if (i == N_NODES - 1) off2[N_NODES] = base[blockIdx.x] + incl;
}

// ---------------- K4: counting-sort scatter (edges grouped by dst) ----------------
__global__ void k_scatter(const int* __restrict__ src, const int* __restrict__ dst,
                          const float* __restrict__ ea, const int* __restrict__ off2,
                          int* __restrict__ cursor, int* __restrict__ ssrc,
                          float* __restrict__ sea) {
  int e = blockIdx.x * 256 + threadIdx.x;
  if (e >= N_EDGES) return;
  int d = dst[e];
  int pos = off2[d] + atomicAdd(&cursor[d], 1);
  ssrc[pos] = src[e];
  sea[pos]  = ea[e];
}

// ---------------- K5: fused prep (xh16 | Wlh | Btp) ----------------
__global__ void k_prep(const float* __restrict__ x, uint4* __restrict__ xh,
                       const float* __restrict__ Wl1, unsigned* __restrict__ Wlh,
                       const float* __restrict__ Wl2, const float* __restrict__ Wr2,
                       unsigned short* __restrict__ Btp) {
  int b = blockIdx.x, t = threadIdx.x;
  if (b < SCAN_BLKS) {                       // x -> packed f16 pairs
    int n = b * 256 + t;
    if (n >= N_NODES) return;
    float4 a = *(const float4*)(x + n * 8);
    float4 c = *(const float4*)(x + n * 8 + 4);
    half2v p0 = {(_Float16)a.x, (_Float16)a.y};
    half2v p1 = {(_Float16)a.z, (_Float16)a.w};
    half2v p2 = {(_Float16)c.x, (_Float16)c.y};
    half2v p3 = {(_Float16)c.z, (_Float16)c.w};
    xh[n] = make_uint4(__builtin_bit_cast(unsigned, p0), __builtin_bit_cast(unsigned, p1),
                       __builtin_bit_cast(unsigned, p2), __builtin_bit_cast(unsigned, p3));
  } else if (b < SCAN_BLKS + 4) {            // Wl1 -> packed f16 k-pairs
    int kp = b - SCAN_BLKS;
    half2v h = {(_Float16)Wl1[(2 * kp) * 256 + t], (_Float16)Wl1[(2 * kp + 1) * 256 + t]};
    Wlh[kp * 256 + t] = __builtin_bit_cast(unsigned, h);
  } else {                                   // [Wl2|Wr2]^T -> Btp bf16
    int nIdx = b - SCAN_BLKS - 4;            // 0..255
    float v = (nIdx < 128) ? Wl2[t * 128 + nIdx] : Wr2[t * 128 + (nIdx - 128)];
    Btp[nIdx * 256 + t] = (unsigned short)f2bf(v);
  }
}

// ---------------- K6: fused GATv2 layer 1 + bias + LN + ELU -> h1 (bf16) ----------
__global__ __launch_bounds__(256) void k_gat1(
    const float* __restrict__ x, const uint4* __restrict__ xh16,
    const unsigned* __restrict__ Wlh,
    const float* __restrict__ Wr, const float* __restrict__ We,
    const float* __restrict__ att,
    const float* __restrict__ b1, const float* __restrict__ g1,
    const float* __restrict__ be1,
    const int* __restrict__ off2, const int* __restrict__ ssrc,
    const float* __restrict__ sea, const int* __restrict__ order,
    unsigned* __restrict__ h1b) {
  int lane = threadIdx.x & 63;
  int wv = __builtin_amdgcn_readfirstlane(threadIdx.x >> 6);
  int n = __builtin_amdgcn_readfirstlane(order[blockIdx.x * 4 + wv]);
  int c0 = lane * 4;

  float4 wev = *(const float4*)(We + c0);
  float4 atv = *(const float4*)(att + c0);

  float xn[8];
  {
    float4 a = *(const float4*)(x + n * 8);
    float4 b = *(const float4*)(x + n * 8 + 4);
    xn[0]=a.x; xn[1]=a.y; xn[2]=a.z; xn[3]=a.w;
    xn[4]=b.x; xn[5]=b.y; xn[6]=b.z; xn[7]=b.w;
  }
  float xr0=0.f, xr1=0.f, xr2=0.f, xr3=0.f;
#pragma unroll
  for (int k = 0; k < 8; ++k) {
    float4 wr = *(const float4*)(Wr + k * 256 + c0);
    xr0 += xn[k]*wr.x; xr1 += xn[k]*wr.y; xr2 += xn[k]*wr.z; xr3 += xn[k]*wr.w;
  }
  uint4 wk0 = *(const uint4*)(Wlh + 0 * 256 + c0);
  uint4 wk1 = *(const uint4*)(Wlh + 1 * 256 + c0);
  uint4 wk2 = *(const uint4*)(Wlh + 2 * 256 + c0);
  uint4 wk3 = *(const uint4*)(Wlh + 3 * 256 + c0);

  int beg   = __builtin_amdgcn_readfirstlane(off2[n]);
  int pairs = __builtin_amdgcn_readfirstlane((off2[n + 1] - beg) >> 1);

  float den = 0.f, ac0=0.f, ac1=0.f, ac2=0.f, ac3=0.f;

  int   sA = __builtin_amdgcn_readfirstlane(ssrc[beg]);
  int   sB = __builtin_amdgcn_readfirstlane(ssrc[beg + 1]);
  float eA = sea[beg], eB = sea[beg + 1];
  uint4 xA = xh16[max(sA, 0)];
  uint4 xB = xh16[max(sB, 0)];

  for (int p = 0; p < pairs; ++p) {
    int   csA = sA, csB = sB;
    float ceA = eA, ceB = eB;
    uint4 cxA = xA, cxB = xB;
    if (p + 1 < pairs) {
      int j = beg + 2 * (p + 1);
      sA = __builtin_amdgcn_readfirstlane(ssrc[j]);
      sB = __builtin_amdgcn_readfirstlane(ssrc[j + 1]);
      eA = sea[j];  eB = sea[j + 1];
      xA = xh16[max(sA, 0)];
      xB = xh16[max(sB, 0)];
    }
    float vA0 = dot8h(cxA, wk0.x, wk1.x, wk2.x, wk3.x);
    float vA1 = dot8h(cxA, wk0.y, wk1.y, wk2.y, wk3.y);
    float vA2 = dot8h(cxA, wk0.z, wk1.z, wk2.z, wk3.z);
    float vA3 = dot8h(cxA, wk0.w, wk1.w, wk2.w, wk3.w);
    float vB0 = dot8h(cxB, wk0.x, wk1.x, wk2.x, wk3.x);
    float vB1 = dot8h(cxB, wk0.y, wk1.y, wk2.y, wk3.y);
    float vB2 = dot8h(cxB, wk0.z, wk1.z, wk2.z, wk3.z);
    float vB3 = dot8h(cxB, wk0.w, wk1.w, wk2.w, wk3.w);

    float mA0 = vA0 + fmaf(ceA, wev.x, xr0); mA0 = fmaxf(mA0, 0.2f*mA0);
    float mA1 = vA1 + fmaf(ceA, wev.y, xr1); mA1 = fmaxf(mA1, 0.2f*mA1);
    float mA2 = vA2 + fmaf(ceA, wev.z, xr2); mA2 = fmaxf(mA2, 0.2f*mA2);
    float mA3 = vA3 + fmaf(ceA, wev.w, xr3); mA3 = fmaxf(mA3, 0.2f*mA3);
    float mB0 = vB0 + fmaf(ceB, wev.x, xr0); mB0 = fmaxf(mB0, 0.2f*mB0);
    float mB1 = vB1 + fmaf(ceB, wev.y, xr1); mB1 = fmaxf(mB1, 0.2f*mB1);
    float mB2 = vB2 + fmaf(ceB, wev.z, xr2); mB2 = fmaxf(mB2, 0.2f*mB2);
    float mB3 = vB3 + fmaf(ceB, wev.w, xr3); mB3 = fmaxf(mB3, 0.2f*mB3);

    float pA = mA0*atv.x + mA1*atv.y + mA2*atv.z + mA3*atv.w;
    float pB = mB0*atv.x + mB1*atv.y + mB2*atv.z + mB3*atv.w;
    pA = red16d(pA);
    pB = red16d(pB);

    float wA = (csA >= 0) ? __expf(pA) : 0.f;
    float wB = (csB >= 0) ? __expf(pB) : 0.f;
    den += wA + wB;
    ac0 = fmaf(wA, vA0, fmaf(wB, vB0, ac0));
    ac1 = fmaf(wA, vA1, fmaf(wB, vB1, ac1));
    ac2 = fmaf(wA, vA2, fmaf(wB, vB2, ac2));
    ac3 = fmaf(wA, vA3, fmaf(wB, vB3, ac3));
  }

  float inv = 1.0f / (den + 1e-16f);
  float4 bv = *(const float4*)(b1 + c0);
  float o0 = ac0*inv + bv.x, o1 = ac1*inv + bv.y;
  float o2 = ac2*inv + bv.z, o3 = ac3*inv + bv.w;
  float mu = red64(o0 + o1 + o2 + o3) * (1.0f / 256.0f);
  float d0 = o0-mu, d1 = o1-mu, d2 = o2-mu, d3 = o3-mu;
  float rstd = rsqrtf(red64(d0*d0 + d1*d1 + d2*d2 + d3*d3) * (1.0f/256.0f) + LN_EPS);
  float4 gv  = *(const float4*)(g1 + c0);
  float4 bev = *(const float4*)(be1 + c0);
  float y0 = d0*rstd*gv.x + bev.x; y0 = y0 > 0.f ? y0 : __expf(y0) - 1.0f;
  float y1 = d1*rstd*gv.y + bev.y; y1 = y1 > 0.f ? y1 : __expf(y1) - 1.0f;
  float y2 = d2*rstd*gv.z + bev.z; y2 = y2 > 0.f ? y2 : __expf(y2) - 1.0f;
  float y3 = d3*rstd*gv.w + bev.w; y3 = y3 > 0.f ? y3 : __expf(y3) - 1.0f;
  unsigned lo = f2bf(y0) | (f2bf(y1) << 16);
  unsigned hi = f2bf(y2) | (f2bf(y3) << 16);
  *(uint2*)(h1b + (size_t)n * 128 + lane * 2) = make_uint2(lo, hi);
}

// ---------------- K7: MFMA GEMM  [xl2|xr2] = h1(bf16) @ Btp^T ----------------
__global__ __launch_bounds__(256) void k_gemm2(
    const unsigned* __restrict__ h1b, const unsigned short* __restrict__ Btp,
    unsigned short* __restrict__ xl2b, float* __restrict__ xr2) {
  __shared__ unsigned short Ash[64][264];
  __shared__ unsigned short Bsh[64][264];
  int t = threadIdx.x;
  int bm0 = blockIdx.x * 64;
  int n0  = blockIdx.y * 64;

#pragma unroll
  for (int i = 0; i < 8; ++i) {
    int idx = t + 256 * i;          // uint4 index; 2048 total
    int row = idx >> 5, c4 = idx & 31;
    int gm = bm0 + row;
    uint4 va = (gm < N_NODES) ? *(const uint4*)(h1b + (size_t)gm * 128 + c4 * 4)
                              : make_uint4(0,0,0,0);
    *(uint4*)(&Ash[row][c4 * 8]) = va;
    uint4 vb = *(const uint4*)((const unsigned*)Btp + (size_t)(n0 + row) * 128 + c4 * 4);
    *(uint4*)(&Bsh[row][c4 * 8]) = vb;
  }
  __syncthreads();

  int lane = t & 63, w = t >> 6;
  int lm = lane & 15, lk = (lane >> 4) * 8;
  f32x4 acc[4];
#pragma unroll
  for (int i = 0; i < 4; ++i) acc[i] = (f32x4){0.f,0.f,0.f,0.f};

#pragma unroll
  for (int kk = 0; kk < 8; ++kk) {
    bf16x8 a = *(const bf16x8*)(&Ash[16*w + lm][kk*32 + lk]);
#pragma unroll
    for (int tt = 0; tt < 4; ++tt) {
      bf16x8 b = *(const bf16x8*)(&Bsh[16*tt + lm][kk*32 + lk]);
      acc[tt] = __builtin_amdgcn_mfma_f32_16x16x32_bf16(a, b, acc[tt], 0, 0, 0);
    }
  }

#pragma unroll
  for (int tt = 0; tt < 4; ++tt) {
#pragma unroll
    for (int r = 0; r < 4; ++r) {
      int node = bm0 + 16*w + (lane >> 4) * 4 + r;
      if (node < N_NODES) {
        int colg = n0 + tt * 16 + lm;
        float v = acc[tt][r];
        if (colg < 128) xl2b[(size_t)node * 128 + colg] = (unsigned short)f2bf(v);
        else            xr2 [(size_t)node * 128 + (colg - 128)] = v;
      }
    }
  }
}

// ---------------- K8: fused GATv2 layer 2 + bias + LN + ELU + pooled atomics ------
__global__ __launch_bounds__(256) void k_gat2(
    const unsigned* __restrict__ xl2b, const float* __restrict__ xr2,
    const float* __restrict__ We, const float* __restrict__ att,
    const float* __restrict__ b2, const float* __restrict__ g2,
    const float* __restrict__ be2,
    const int* __restrict__ off2, const int* __restrict__ ssrc,
    const float* __restrict__ sea,
    const int* __restrict__ batch, const int* __restrict__ order,
    float* __restrict__ pool, float* __restrict__ cnt) {
  int tid = threadIdx.x;
  int lane = tid & 63;
  int wv = __builtin_amdgcn_readfirstlane(tid >> 6);
  int row = lane >> 4, col = lane & 15;
  int n = __builtin_amdgcn_readfirstlane(order[blockIdx.x * 4 + wv]);
  int c0 = col * 8;               // 8 channels per lane
  int cu0 = col * 4;              // uint offset into bf16-packed row

  float wev[8], at[8], xr[8];
  *(float4*)(wev)     = *(const float4*)(We + c0);
  *(float4*)(wev + 4) = *(const float4*)(We + c0 + 4);
  *(float4*)(at)      = *(const float4*)(att + c0);
  *(float4*)(at + 4)  = *(const float4*)(att + c0 + 4);
  *(float4*)(xr)      = *(const float4*)(xr2 + (size_t)n * 128 + c0);
  *(float4*)(xr + 4)  = *(const float4*)(xr2 + (size_t)n * 128 + c0 + 4);

  int beg   = __builtin_amdgcn_readfirstlane(off2[n]);
  int quads = __builtin_amdgcn_readfirstlane((off2[n + 1] - beg) >> 2);  // >= 1

  float den = 0.f;
  float ac[8] = {0,0,0,0,0,0,0,0};

  // depth-3 pipeline; each row of 16 lanes owns one edge per quad
  int s0 = -1, s1 = -1, s2 = -1;
  float e0 = 0.f, e1 = 0.f, e2 = 0.f;
  uint4 u0 = make_uint4(0,0,0,0), u1 = u0, u2 = u0;
  {
    s0 = ssrc[beg + row]; e0 = sea[beg + row];
    u0 = *(const uint4*)(xl2b + (size_t)max(s0, 0) * 64 + cu0);
  }
  if (quads > 1) {
    s1 = ssrc[beg + 4 + row]; e1 = sea[beg + 4 + row];
    u1 = *(const uint4*)(xl2b + (size_t)max(s1, 0) * 64 + cu0);
  }
  if (quads > 2) {
    s2 = ssrc[beg + 8 + row]; e2 = sea[beg + 8 + row];
    u2 = *(const uint4*)(xl2b + (size_t)max(s2, 0) * 64 + cu0);
  }

  for (int q = 0; q < quads; ++q) {
    int cs = s0; float ce = e0; uint4 cu = u0;
    s0 = s1; e0 = e1; u0 = u1;
    s1 = s2; e1 = e2; u1 = u2;
    if (q + 3 < quads) {
      int j = beg + (q + 3) * 4 + row;
      s2 = ssrc[j]; e2 = sea[j];
      u2 = *(const uint4*)(xl2b + (size_t)max(s2, 0) * 64 + cu0);
    }
    float v[8];
    v[0]=bflo(cu.x); v[1]=bfhi(cu.x); v[2]=bflo(cu.y); v[3]=bfhi(cu.y);
    v[4]=bflo(cu.z); v[5]=bfhi(cu.z); v[6]=bflo(cu.w); v[7]=bfhi(cu.w);
    float p = 0.f;
#pragma unroll
    for (int j = 0; j < 8; ++j) {
      float m = v[j] + fmaf(ce, wev[j], xr[j]);
      m = fmaxf(m, 0.2f * m);
      p = fmaf(m, at[j], p);
    }
    p = red16d(p);
    float w = (cs >= 0) ? __expf(p) : 0.f;
    den += w;
#pragma unroll
    for (int j = 0; j < 8; ++j) ac[j] = fmaf(w, v[j], ac[j]);
  }
  den += __shfl_xor(den, 16); den += __shfl_xor(den, 32);
#pragma unroll
  for (int j = 0; j < 8; ++j) {
    ac[j] += __shfl_xor(ac[j], 16);
    ac[j] += __shfl_xor(ac[j], 32);
  }

  float inv = 1.0f / (den + 1e-16f);
  float o[8], y[8];
  float bv[8], gv[8], bev[8];
  *(float4*)(bv)      = *(const float4*)(b2 + c0);
  *(float4*)(bv + 4)  = *(const float4*)(b2 + c0 + 4);
  *(float4*)(gv)      = *(const float4*)(g2 + c0);
  *(float4*)(gv + 4)  = *(const float4*)(g2 + c0 + 4);
  *(float4*)(bev)     = *(const float4*)(be2 + c0);
  *(float4*)(bev + 4) = *(const float4*)(be2 + c0 + 4);
  float osum = 0.f;
#pragma unroll
  for (int j = 0; j < 8; ++j) { o[j] = ac[j] * inv + bv[j]; osum += o[j]; }
  float mu = red64(osum) * (1.0f / 512.0f);
  float vsum = 0.f;
#pragma unroll
  for (int j = 0; j < 8; ++j) { o[j] -= mu; vsum += o[j] * o[j]; }
  float rstd = rsqrtf(red64(vsum) * (1.0f / 512.0f) + LN_EPS);
#pragma unroll
  for (int j = 0; j < 8; ++j) {
    float t2 = o[j] * rstd * gv[j] + bev[j];
    y[j] = t2 > 0.f ? t2 : __expf(t2) - 1.0f;
  }

  // block-level pool dedup (order mixes graphs; dedup still correct, just fewer hits)
  __shared__ float pbuf[4][128];
  __shared__ int gbuf[4];
  if (row == 0) {
#pragma unroll
    for (int j = 0; j < 8; ++j) pbuf[wv][c0 + j] = y[j];
  }
  if (lane == 0) gbuf[wv] = batch[n];
  __syncthreads();
  if (wv == 0) {
    int r = blockIdx.x & (NREP - 1);
    int ch = lane;                       // handles ch and ch+64
    float acc0 = pbuf[0][ch], acc1 = pbuf[0][ch+64];
    int cg = gbuf[0], cn = 1;
#pragma unroll
    for (int i = 1; i < 4; ++i) {
      if (gbuf[i] == cg) { acc0 += pbuf[i][ch]; acc1 += pbuf[i][ch+64]; cn++; }
      else {
        float* pp = pool + ((size_t)(r * N_GRAPHS + cg)) * 128;
        atomicAdd(pp + ch, acc0); atomicAdd(pp + ch + 64, acc1);
        if (lane == 0) atomicAdd(&cnt[r * N_GRAPHS + cg], (float)cn);
        cg = gbuf[i]; acc0 = pbuf[i][ch]; acc1 = pbuf[i][ch+64]; cn = 1;
      }
    }
    float* pp = pool + ((size_t)(r * N_GRAPHS + cg)) * 128;
    atomicAdd(pp + ch, acc0); atomicAdd(pp + ch + 64, acc1);
    if (lane == 0) atomicAdd(&cnt[r * N_GRAPHS + cg], (float)cn);
  }
}

// ---------------- K9: reduce replicas, divide by count ----------------
__global__ void k_final(const float* __restrict__ pool, const float* __restrict__ cnt,
                        float* __restrict__ out) {
  int idx = blockIdx.x * 256 + threadIdx.x;
  if (idx >= N_GRAPHS * 128) return;
  int g = idx >> 7, c = idx & 127;
  float s = 0.f, nn = 0.f;
#pragma unroll
  for (int r = 0; r < NREP; ++r) {
    s  += pool[((size_t)(r * N_GRAPHS + g)) * 128 + c];
    nn += cnt[r * N_GRAPHS + g];
  }
  out[idx] = s / fmaxf(nn, 1.0f);
}

// ---------------- launch ----------------
extern "C" void kernel_launch(void* const* d_in, const int* in_sizes, int n_in,
                              void* d_out, int out_size, void* d_ws, size_t ws_size,
                              hipStream_t stream) {
  const float* x    = (const float*)d_in[0];
  const int*   ei   = (const int*)  d_in[1];
  const float* ea   = (const float*)d_in[2];
  const int*   batch= (const int*)  d_in[3];
  const float* Wl1  = (const float*)d_in[4];
  const float* Wr1  = (const float*)d_in[5];
  const float* We1  = (const float*)d_in[6];
  const float* att1 = (const float*)d_in[7];
  const float* b1   = (const float*)d_in[8];
  const float* g1   = (const float*)d_in[9];
  const float* be1  = (const float*)d_in[10];
  const float* Wl2  = (const float*)d_in[11];
  const float* Wr2  = (const float*)d_in[12];
  const float* We2  = (const float*)d_in[13];
  const float* att2 = (const float*)d_in[14];
  const float* b2   = (const float*)d_in[15];
  const float* g2   = (const float*)d_in[16];
  const float* be2  = (const float*)d_in[17];
  const int* srcp = ei;
  const int* dstp = ei + N_EDGES;

  const int MAXE2 = N_EDGES + 4 * N_NODES;

  char* ws = (char*)d_ws;
  size_t off = 0;
  auto alloc = [&](size_t bytes) {
    char* p = ws + off; off += (bytes + 15) & ~(size_t)15; return p;
  };
  // --- zeroed region start ---
  int*            deg   = (int*)           alloc((size_t)N_NODES * 4);
  float*          easum = (float*)         alloc((size_t)N_NODES * 4);
  int*            cursor= (int*)           alloc((size_t)N_NODES * 4);
  int*            dh    = (int*)           alloc((size_t)DBINS * 4);
  int*            dcur  = (int*)           alloc((size_t)DBINS * 4);
  // --- zeroed region end ---
  int*            off2  = (int*)           alloc((size_t)(N_NODES + 1) * 4);
  int*            part  = (int*)           alloc((size_t)256 * 4);
  int*            base  = (int*)           alloc((size_t)257 * 4);
  int*            dbase = (int*)           alloc((size_t)DBINS * 4);
  int*            order = (int*)           alloc((size_t)N_NODES * 4);
  int*            ssrc  = (int*)           alloc((size_t)MAXE2 * 4);
  float*          sea   = (float*)         alloc((size_t)MAXE2 * 4);
  uint4*          xh16  = (uint4*)         alloc((size_t)N_NODES * 16);
  unsigned*       Wlh   = (unsigned*)      alloc((size_t)4 * 256 * 4);
  unsigned*       h1b   = (unsigned*)      alloc((size_t)N_NODES * 128 * 4);  // bf16 256ch
  unsigned short* xl2b  = (unsigned short*)alloc((size_t)N_NODES * 128 * 2);  // bf16 128ch
  float*          xr2   = (float*)         alloc((size_t)N_NODES * 128 * 4);
  unsigned short* Btp   = (unsigned short*)alloc((size_t)256 * 256 * 2);
  float*          pool  = (float*)         alloc((size_t)NREP * N_GRAPHS * 128 * 4);
  float*          cnt   = (float*)         alloc((size_t)NREP * N_GRAPHS * 4);

  (void)hipMemsetAsync(deg, 0, (char*)off2 - (char*)deg, stream);  // deg..dcur
  (void)hipMemsetAsync(pool, 0, ((char*)cnt + (((size_t)NREP*N_GRAPHS*4 + 15) & ~(size_t)15))
                           - (char*)pool, stream);

  k_hist    <<<N_EDGES / 256, 256, 0, stream>>>(dstp, ea, deg, easum);
  k_prep    <<<SCAN_BLKS + 4 + 256, 256, 0, stream>>>(x, xh16, Wl1, Wlh, Wl2, Wr2, Btp);
  k_dhist   <<<SCAN_BLKS, 256, 0, stream>>>(deg, dh);
  k_dscan   <<<1, DBINS, 0, stream>>>(dh, dbase);
  k_dscatter<<<SCAN_BLKS, 256, 0, stream>>>(deg, dbase, dcur, order);
  k_scanA   <<<SCAN_BLKS, 256, 0, stream>>>(deg, part);
  k_scanB   <<<1, 256, 0, stream>>>(part, base);
  k_scanC   <<<SCAN_BLKS, 256, 0, stream>>>(deg, base, easum, off2, ssrc, sea);
  k_scatter <<<N_EDGES / 256, 256, 0, stream>>>(srcp, dstp, ea, off2, cursor, ssrc, sea);
  k_gat1    <<<N_NODES / 4, 256, 0, stream>>>(x, xh16, Wlh, Wr1, We1, att1, b1, g1, be1,
                                              off2, ssrc, sea, order, h1b);
  dim3 g7((N_NODES + 63) / 64, 4);
  k_gemm2   <<<g7, 256, 0, stream>>>(h1b, Btp, xl2b, xr2);
  k_gat2    <<<N_NODES / 4, 256, 0, stream>>>((const unsigned*)xl2b, xr2, We2, att2,
                                              b2, g2, be2,
                                              off2, ssrc, sea, batch, order, pool, cnt);
  k_final   <<<(N_GRAPHS * 128) / 256, 256, 0, stream>>>(pool, cnt, (float*)d_out);
}

// Round 10
// 437.208 us; speedup vs baseline: 1.5129x; 1.5129x over previous
//
#include <hip/hip_runtime.h>
#include <math.h>

#define N_NODES 50000
#define N_EDGES 800000
#define N_GRAPHS 64
#define NREP 32
#define LN_EPS 1e-5f
#define SCAN_BLKS 196          // ceil(50000/256)

typedef __attribute__((ext_vector_type(8))) short bf16x8;
typedef __attribute__((ext_vector_type(4))) float f32x4;
typedef __attribute__((ext_vector_type(2))) _Float16 half2v;

// ---------------- DPP-based reductions (no LDS latency) ----------------
template <int CTRL>
__device__ __forceinline__ float dppadd(float v) {
  int t = __builtin_amdgcn_update_dpp(0, __float_as_int(v), CTRL, 0xF, 0xF, true);
  return v + __int_as_float(t);
}
__device__ __forceinline__ float red16d(float p) {
  p = dppadd<0xB1>(p);   // quad_perm [1,0,3,2]
  p = dppadd<0x4E>(p);   // quad_perm [2,3,0,1]
  p = dppadd<0x141>(p);  // row_half_mirror
  p = dppadd<0x140>(p);  // row_mirror
  return p;
}
__device__ __forceinline__ float red64(float p) {
  p = red16d(p);
  p += __shfl_xor(p, 16); p += __shfl_xor(p, 32);
  return p;
}

__device__ __forceinline__ unsigned f2bf(float f) {  // rne f32->bf16
  unsigned u = __float_as_uint(f);
  return (u + 0x7fffu + ((u >> 16) & 1u)) >> 16;
}
__device__ __forceinline__ float bflo(unsigned u) { return __uint_as_float(u << 16); }
__device__ __forceinline__ float bfhi(unsigned u) { return __uint_as_float(u & 0xffff0000u); }

__device__ __forceinline__ half2v u2h(unsigned u) {
  return __builtin_bit_cast(half2v, u);
}
__device__ __forceinline__ float dot8h(uint4 xh, unsigned w0, unsigned w1,
                                       unsigned w2, unsigned w3) {
#if __has_builtin(__builtin_amdgcn_fdot2)
  float s = __builtin_amdgcn_fdot2(u2h(xh.x), u2h(w0), 0.f, false);
  s = __builtin_amdgcn_fdot2(u2h(xh.y), u2h(w1), s, false);
  s = __builtin_amdgcn_fdot2(u2h(xh.z), u2h(w2), s, false);
  s = __builtin_amdgcn_fdot2(u2h(xh.w), u2h(w3), s, false);
  return s;
#else
  float s = 0.f;
  half2v a;
  a = u2h(xh.x); { half2v b = u2h(w0); s += (float)a.x*(float)b.x + (float)a.y*(float)b.y; }
  a = u2h(xh.y); { half2v b = u2h(w1); s += (float)a.x*(float)b.x + (float)a.y*(float)b.y; }
  a = u2h(xh.z); { half2v b = u2h(w2); s += (float)a.x*(float)b.x + (float)a.y*(float)b.y; }
  a = u2h(xh.w); { half2v b = u2h(w3); s += (float)a.x*(float)b.x + (float)a.y*(float)b.y; }
  return s;
#endif
}

// ---------------- K1: per-dst degree + edge_attr sum ----------------
__global__ void k_hist(const int* __restrict__ dst, const float* __restrict__ ea,
                       int* __restrict__ deg, float* __restrict__ easum) {
  int e = blockIdx.x * 256 + threadIdx.x;
  if (e >= N_EDGES) return;
  int d = dst[e];
  atomicAdd(&deg[d], 1);
  atomicAdd(&easum[d], ea[e]);
}

// ---------------- K2: multi-block exclusive scan of quad-padded lengths ----------
__global__ void k_scanA(const int* __restrict__ deg, int* __restrict__ part) {
  int t = threadIdx.x;
  int i = blockIdx.x * 256 + t;
  int len = (i < N_NODES) ? ((deg[i] + 4) & ~3) : 0;
  __shared__ int sm[256];
  sm[t] = len; __syncthreads();
  for (int o = 128; o > 0; o >>= 1) {
    if (t < o) sm[t] += sm[t + o];
    __syncthreads();
  }
  if (t == 0) part[blockIdx.x] = sm[0];
}
__global__ void k_scanB(const int* __restrict__ part, int* __restrict__ base) {
  int t = threadIdx.x;                 // 256 threads, 1 block
  __shared__ int sm[256];
  int v = (t < SCAN_BLKS) ? part[t] : 0;
  sm[t] = v; __syncthreads();
  for (int o = 1; o < 256; o <<= 1) {
    int u = (t >= o) ? sm[t - o] : 0;
    __syncthreads();
    sm[t] += u;
    __syncthreads();
  }
  base[t] = (t == 0) ? 0 : sm[t - 1];  // exclusive
}
// scanC fused with self-loop + sentinel-pad writes
__global__ void k_scanC(const int* __restrict__ deg, const int* __restrict__ base,
                        const float* __restrict__ easum,
                        int* __restrict__ off2,
                        int* __restrict__ ssrc, float* __restrict__ sea) {
  int t = threadIdx.x;
  int i = blockIdx.x * 256 + t;
  int d = (i < N_NODES) ? deg[i] : 0;
  int len = (i < N_NODES) ? ((d + 4) & ~3) : 0;
  __shared__ int sm[256];
  sm[t] = len; __syncthreads();
  for (int o = 1; o < 256; o <<= 1) {
    int u = (t >= o) ? sm[t - o] : 0;
    __syncthreads();
    sm[t] += u;
    __syncthreads();
  }
  int incl = sm[t];
  if (i < N_NODES) {
    int b = base[blockIdx.x] + incl - len;
    off2[i] = b;
    ssrc[b + d] = i;
    sea[b + d]  = easum[i] / fmaxf((float)d, 1.0f);
    for (int j = d + 1; j < len; ++j) { ssrc[b + j] = -1; sea[b + j] = 0.f; }
  }
  if (i == N_NODES - 1) off2[N_NODES] = base[blockIdx.x] + incl;
}

// ---------------- K4: counting-sort scatter (edges grouped by dst) ----------------
__global__ void k_scatter(const int* __restrict__ src, const int* __restrict__ dst,
                          const float* __restrict__ ea, const int* __restrict__ off2,
                          int* __restrict__ cursor, int* __restrict__ ssrc,
                          float* __restrict__ sea) {
  int e = blockIdx.x * 256 + threadIdx.x;
  if (e >= N_EDGES) return;
  int d = dst[e];
  int pos = off2[d] + atomicAdd(&cursor[d], 1);
  ssrc[pos] = src[e];
  sea[pos]  = ea[e];
}

// ---------------- K5: fused prep (xh16 | Wlh | Btp) ----------------
__global__ void k_prep(const float* __restrict__ x, uint4* __restrict__ xh,
                       const float* __restrict__ Wl1, unsigned* __restrict__ Wlh,
                       const float* __restrict__ Wl2, const float* __restrict__ Wr2,
                       unsigned short* __restrict__ Btp) {
  int b = blockIdx.x, t = threadIdx.x;
  if (b < SCAN_BLKS) {                       // x -> packed f16 pairs
    int n = b * 256 + t;
    if (n >= N_NODES) return;
    float4 a = *(const float4*)(x + n * 8);
    float4 c = *(const float4*)(x + n * 8 + 4);
    half2v p0 = {(_Float16)a.x, (_Float16)a.y};
    half2v p1 = {(_Float16)a.z, (_Float16)a.w};
    half2v p2 = {(_Float16)c.x, (_Float16)c.y};
    half2v p3 = {(_Float16)c.z, (_Float16)c.w};
    xh[n] = make_uint4(__builtin_bit_cast(unsigned, p0), __builtin_bit_cast(unsigned, p1),
                       __builtin_bit_cast(unsigned, p2), __builtin_bit_cast(unsigned, p3));
  } else if (b < SCAN_BLKS + 4) {            // Wl1 -> packed f16 k-pairs
    int kp = b - SCAN_BLKS;
    half2v h = {(_Float16)Wl1[(2 * kp) * 256 + t], (_Float16)Wl1[(2 * kp + 1) * 256 + t]};
    Wlh[kp * 256 + t] = __builtin_bit_cast(unsigned, h);
  } else {                                   // [Wl2|Wr2]^T -> Btp bf16
    int nIdx = b - SCAN_BLKS - 4;            // 0..255
    float v = (nIdx < 128) ? Wl2[t * 128 + nIdx] : Wr2[t * 128 + (nIdx - 128)];
    Btp[nIdx * 256 + t] = (unsigned short)f2bf(v);
  }
}

// ---------------- K6: fused GATv2 layer 1 + bias + LN + ELU -> h1 (bf16) ----------
__global__ __launch_bounds__(256) void k_gat1(
    const float* __restrict__ x, const uint4* __restrict__ xh16,
    const unsigned* __restrict__ Wlh,
    const float* __restrict__ Wr, const float* __restrict__ We,
    const float* __restrict__ att,
    const float* __restrict__ b1, const float* __restrict__ g1,
    const float* __restrict__ be1,
    const int* __restrict__ off2, const int* __restrict__ ssrc,
    const float* __restrict__ sea, unsigned* __restrict__ h1b) {
  int lane = threadIdx.x & 63;
  int wv = __builtin_amdgcn_readfirstlane(threadIdx.x >> 6);
  int n = blockIdx.x * 4 + wv;
  int c0 = lane * 4;

  float4 wev = *(const float4*)(We + c0);
  float4 atv = *(const float4*)(att + c0);

  float xn[8];
  {
    float4 a = *(const float4*)(x + n * 8);
    float4 b = *(const float4*)(x + n * 8 + 4);
    xn[0]=a.x; xn[1]=a.y; xn[2]=a.z; xn[3]=a.w;
    xn[4]=b.x; xn[5]=b.y; xn[6]=b.z; xn[7]=b.w;
  }
  float xr0=0.f, xr1=0.f, xr2=0.f, xr3=0.f;
#pragma unroll
  for (int k = 0; k < 8; ++k) {
    float4 wr = *(const float4*)(Wr + k * 256 + c0);
    xr0 += xn[k]*wr.x; xr1 += xn[k]*wr.y; xr2 += xn[k]*wr.z; xr3 += xn[k]*wr.w;
  }
  uint4 wk0 = *(const uint4*)(Wlh + 0 * 256 + c0);
  uint4 wk1 = *(const uint4*)(Wlh + 1 * 256 + c0);
  uint4 wk2 = *(const uint4*)(Wlh + 2 * 256 + c0);
  uint4 wk3 = *(const uint4*)(Wlh + 3 * 256 + c0);

  int beg   = __builtin_amdgcn_readfirstlane(off2[n]);
  int pairs = __builtin_amdgcn_readfirstlane((off2[n + 1] - beg) >> 1);

  float den = 0.f, ac0=0.f, ac1=0.f, ac2=0.f, ac3=0.f;

  int   sA = __builtin_amdgcn_readfirstlane(ssrc[beg]);
  int   sB = __builtin_amdgcn_readfirstlane(ssrc[beg + 1]);
  float eA = sea[beg], eB = sea[beg + 1];
  uint4 xA = xh16[max(sA, 0)];
  uint4 xB = xh16[max(sB, 0)];

  for (int p = 0; p < pairs; ++p) {
    int   csA = sA, csB = sB;
    float ceA = eA, ceB = eB;
    uint4 cxA = xA, cxB = xB;
    if (p + 1 < pairs) {
      int j = beg + 2 * (p + 1);
      sA = __builtin_amdgcn_readfirstlane(ssrc[j]);
      sB = __builtin_amdgcn_readfirstlane(ssrc[j + 1]);
      eA = sea[j];  eB = sea[j + 1];
      xA = xh16[max(sA, 0)];
      xB = xh16[max(sB, 0)];
    }
    float vA0 = dot8h(cxA, wk0.x, wk1.x, wk2.x, wk3.x);
    float vA1 = dot8h(cxA, wk0.y, wk1.y, wk2.y, wk3.y);
    float vA2 = dot8h(cxA, wk0.z, wk1.z, wk2.z, wk3.z);
    float vA3 = dot8h(cxA, wk0.w, wk1.w, wk2.w, wk3.w);
    float vB0 = dot8h(cxB, wk0.x, wk1.x, wk2.x, wk3.x);
    float vB1 = dot8h(cxB, wk0.y, wk1.y, wk2.y, wk3.y);
    float vB2 = dot8h(cxB, wk0.z, wk1.z, wk2.z, wk3.z);
    float vB3 = dot8h(cxB, wk0.w, wk1.w, wk2.w, wk3.w);

    float mA0 = vA0 + fmaf(ceA, wev.x, xr0); mA0 = fmaxf(mA0, 0.2f*mA0);
    float mA1 = vA1 + fmaf(ceA, wev.y, xr1); mA1 = fmaxf(mA1, 0.2f*mA1);
    float mA2 = vA2 + fmaf(ceA, wev.z, xr2); mA2 = fmaxf(mA2, 0.2f*mA2);
    float mA3 = vA3 + fmaf(ceA, wev.w, xr3); mA3 = fmaxf(mA3, 0.2f*mA3);
    float mB0 = vB0 + fmaf(ceB, wev.x, xr0); mB0 = fmaxf(mB0, 0.2f*mB0);
    float mB1 = vB1 + fmaf(ceB, wev.y, xr1); mB1 = fmaxf(mB1, 0.2f*mB1);
    float mB2 = vB2 + fmaf(ceB, wev.z, xr2); mB2 = fmaxf(mB2, 0.2f*mB2);
    float mB3 = vB3 + fmaf(ceB, wev.w, xr3); mB3 = fmaxf(mB3, 0.2f*mB3);

    float pA = mA0*atv.x + mA1*atv.y + mA2*atv.z + mA3*atv.w;
    float pB = mB0*atv.x + mB1*atv.y + mB2*atv.z + mB3*atv.w;
    pA = red16d(pA);
    pB = red16d(pB);

    float wA = (csA >= 0) ? __expf(pA) : 0.f;
    float wB = (csB >= 0) ? __expf(pB) : 0.f;
    den += wA + wB;
    ac0 = fmaf(wA, vA0, fmaf(wB, vB0, ac0));
    ac1 = fmaf(wA, vA1, fmaf(wB, vB1, ac1));
    ac2 = fmaf(wA, vA2, fmaf(wB, vB2, ac2));
    ac3 = fmaf(wA, vA3, fmaf(wB, vB3, ac3));
  }

  float inv = 1.0f / (den + 1e-16f);
  float4 bv = *(const float4*)(b1 + c0);
  float o0 = ac0*inv + bv.x, o1 = ac1*inv + bv.y;
  float o2 = ac2*inv + bv.z, o3 = ac3*inv + bv.w;
  float mu = red64(o0 + o1 + o2 + o3) * (1.0f / 256.0f);
  float d0 = o0-mu, d1 = o1-mu, d2 = o2-mu, d3 = o3-mu;
  float rstd = rsqrtf(red64(d0*d0 + d1*d1 + d2*d2 + d3*d3) * (1.0f/256.0f) + LN_EPS);
  float4 gv  = *(const float4*)(g1 + c0);
  float4 bev = *(const float4*)(be1 + c0);
  float y0 = d0*rstd*gv.x + bev.x; y0 = y0 > 0.f ? y0 : __expf(y0) - 1.0f;
  float y1 = d1*rstd*gv.y + bev.y; y1 = y1 > 0.f ? y1 : __expf(y1) - 1.0f;
  float y2 = d2*rstd*gv.z + bev.z; y2 = y2 > 0.f ? y2 : __expf(y2) - 1.0f;
  float y3 = d3*rstd*gv.w + bev.w; y3 = y3 > 0.f ? y3 : __expf(y3) - 1.0f;
  unsigned lo = f2bf(y0) | (f2bf(y1) << 16);
  unsigned hi = f2bf(y2) | (f2bf(y3) << 16);
  *(uint2*)(h1b + (size_t)n * 128 + lane * 2) = make_uint2(lo, hi);
}

// ---------------- K7: MFMA GEMM  [xl2|xr2] = h1(bf16) @ Btp^T ----------------
__global__ __launch_bounds__(256) void k_gemm2(
    const unsigned* __restrict__ h1b, const unsigned short* __restrict__ Btp,
    unsigned short* __restrict__ xl2b, float* __restrict__ xr2) {
  __shared__ unsigned short Ash[64][264];
  __shared__ unsigned short Bsh[64][264];
  int t = threadIdx.x;
  int bm0 = blockIdx.x * 64;
  int n0  = blockIdx.y * 64;

#pragma unroll
  for (int i = 0; i < 8; ++i) {
    int idx = t + 256 * i;          // uint4 index; 2048 total
    int row = idx >> 5, c4 = idx & 31;
    int gm = bm0 + row;
    uint4 va = (gm < N_NODES) ? *(const uint4*)(h1b + (size_t)gm * 128 + c4 * 4)
                              : make_uint4(0,0,0,0);
    *(uint4*)(&Ash[row][c4 * 8]) = va;
    uint4 vb = *(const uint4*)((const unsigned*)Btp + (size_t)(n0 + row) * 128 + c4 * 4);
    *(uint4*)(&Bsh[row][c4 * 8]) = vb;
  }
  __syncthreads();

  int lane = t & 63, w = t >> 6;
  int lm = lane & 15, lk = (lane >> 4) * 8;
  f32x4 acc[4];
#pragma unroll
  for (int i = 0; i < 4; ++i) acc[i] = (f32x4){0.f,0.f,0.f,0.f};

#pragma unroll
  for (int kk = 0; kk < 8; ++kk) {
    bf16x8 a = *(const bf16x8*)(&Ash[16*w + lm][kk*32 + lk]);
#pragma unroll
    for (int tt = 0; tt < 4; ++tt) {
      bf16x8 b = *(const bf16x8*)(&Bsh[16*tt + lm][kk*32 + lk]);
      acc[tt] = __builtin_amdgcn_mfma_f32_16x16x32_bf16(a, b, acc[tt], 0, 0, 0);
    }
  }

#pragma unroll
  for (int tt = 0; tt < 4; ++tt) {
#pragma unroll
    for (int r = 0; r < 4; ++r) {
      int node = bm0 + 16*w + (lane >> 4) * 4 + r;
      if (node < N_NODES) {
        int colg = n0 + tt * 16 + lm;
        float v = acc[tt][r];
        if (colg < 128) xl2b[(size_t)node * 128 + colg] = (unsigned short)f2bf(v);
        else            xr2 [(size_t)node * 128 + (colg - 128)] = v;
      }
    }
  }
}

// ---------------- K8: fused GATv2 layer 2 + bias + LN + ELU + pooled atomics ------
__global__ __launch_bounds__(256) void k_gat2(
    const unsigned* __restrict__ xl2b, const float* __restrict__ xr2,
    const float* __restrict__ We, const float* __restrict__ att,
    const float* __restrict__ b2, const float* __restrict__ g2,
    const float* __restrict__ be2,
    const int* __restrict__ off2, const int* __restrict__ ssrc,
    const float* __restrict__ sea,
    const int* __restrict__ batch,
    float* __restrict__ pool, float* __restrict__ cnt) {
  int tid = threadIdx.x;
  int lane = tid & 63;
  int wv = __builtin_amdgcn_readfirstlane(tid >> 6);
  int row = lane >> 4, col = lane & 15;
  int n = blockIdx.x * 4 + wv;
  int c0 = col * 8;               // 8 channels per lane
  int cu0 = col * 4;              // uint offset into bf16-packed row

  float wev[8], at[8], xr[8];
  *(float4*)(wev)     = *(const float4*)(We + c0);
  *(float4*)(wev + 4) = *(const float4*)(We + c0 + 4);
  *(float4*)(at)      = *(const float4*)(att + c0);
  *(float4*)(at + 4)  = *(const float4*)(att + c0 + 4);
  *(float4*)(xr)      = *(const float4*)(xr2 + (size_t)n * 128 + c0);
  *(float4*)(xr + 4)  = *(const float4*)(xr2 + (size_t)n * 128 + c0 + 4);

  int beg   = __builtin_amdgcn_readfirstlane(off2[n]);
  int quads = __builtin_amdgcn_readfirstlane((off2[n + 1] - beg) >> 2);  // >= 1

  float den = 0.f;
  float ac[8] = {0,0,0,0,0,0,0,0};

  // depth-3 pipeline; each row of 16 lanes owns one edge per quad
  int s0 = -1, s1 = -1, s2 = -1;
  float e0 = 0.f, e1 = 0.f, e2 = 0.f;
  uint4 u0 = make_uint4(0,0,0,0), u1 = u0, u2 = u0;
  {
    s0 = ssrc[beg + row]; e0 = sea[beg + row];
    u0 = *(const uint4*)(xl2b + (size_t)max(s0, 0) * 64 + cu0);
  }
  if (quads > 1) {
    s1 = ssrc[beg + 4 + row]; e1 = sea[beg + 4 + row];
    u1 = *(const uint4*)(xl2b + (size_t)max(s1, 0) * 64 + cu0);
  }
  if (quads > 2) {
    s2 = ssrc[beg + 8 + row]; e2 = sea[beg + 8 + row];
    u2 = *(const uint4*)(xl2b + (size_t)max(s2, 0) * 64 + cu0);
  }

  for (int q = 0; q < quads; ++q) {
    int cs = s0; float ce = e0; uint4 cu = u0;
    s0 = s1; e0 = e1; u0 = u1;
    s1 = s2; e1 = e2; u1 = u2;
    if (q + 3 < quads) {
      int j = beg + (q + 3) * 4 + row;
      s2 = ssrc[j]; e2 = sea[j];
      u2 = *(const uint4*)(xl2b + (size_t)max(s2, 0) * 64 + cu0);
    }
    float v[8];
    v[0]=bflo(cu.x); v[1]=bfhi(cu.x); v[2]=bflo(cu.y); v[3]=bfhi(cu.y);
    v[4]=bflo(cu.z); v[5]=bfhi(cu.z); v[6]=bflo(cu.w); v[7]=bfhi(cu.w);
    float p = 0.f;
#pragma unroll
    for (int j = 0; j < 8; ++j) {
      float m = v[j] + fmaf(ce, wev[j], xr[j]);
      m = fmaxf(m, 0.2f * m);
      p = fmaf(m, at[j], p);
    }
    p = red16d(p);
    float w = (cs >= 0) ? __expf(p) : 0.f;
    den += w;
#pragma unroll
    for (int j = 0; j < 8; ++j) ac[j] = fmaf(w, v[j], ac[j]);
  }
  den += __shfl_xor(den, 16); den += __shfl_xor(den, 32);
#pragma unroll
  for (int j = 0; j < 8; ++j) {
    ac[j] += __shfl_xor(ac[j], 16);
    ac[j] += __shfl_xor(ac[j], 32);
  }

  float inv = 1.0f / (den + 1e-16f);
  float o[8], y[8];
  float bv[8], gv[8], bev[8];
  *(float4*)(bv)      = *(const float4*)(b2 + c0);
  *(float4*)(bv + 4)  = *(const float4*)(b2 + c0 + 4);
  *(float4*)(gv)      = *(const float4*)(g2 + c0);
  *(float4*)(gv + 4)  = *(const float4*)(g2 + c0 + 4);
  *(float4*)(bev)     = *(const float4*)(be2 + c0);
  *(float4*)(bev + 4) = *(const float4*)(be2 + c0 + 4);
  float osum = 0.f;
#pragma unroll
  for (int j = 0; j < 8; ++j) { o[j] = ac[j] * inv + bv[j]; osum += o[j]; }
  float mu = red64(osum) * (1.0f / 512.0f);
  float vsum = 0.f;
#pragma unroll
  for (int j = 0; j < 8; ++j) { o[j] -= mu; vsum += o[j] * o[j]; }
  float rstd = rsqrtf(red64(vsum) * (1.0f / 512.0f) + LN_EPS);
#pragma unroll
  for (int j = 0; j < 8; ++j) {
    float t2 = o[j] * rstd * gv[j] + bev[j];
    y[j] = t2 > 0.f ? t2 : __expf(t2) - 1.0f;
  }

  // block-level pool dedup (batch sorted -> usually 1 graph per block)
  __shared__ float pbuf[4][128];
  __shared__ int gbuf[4];
  if (row == 0) {
#pragma unroll
    for (int j = 0; j < 8; ++j) pbuf[wv][c0 + j] = y[j];
  }
  if (lane == 0) gbuf[wv] = batch[n];
  __syncthreads();
  if (wv == 0) {
    int r = blockIdx.x & (NREP - 1);
    int ch = lane;                       // handles ch and ch+64
    float acc0 = pbuf[0][ch], acc1 = pbuf[0][ch+64];
    int cg = gbuf[0], cn = 1;
#pragma unroll
    for (int i = 1; i < 4; ++i) {
      if (gbuf[i] == cg) { acc0 += pbuf[i][ch]; acc1 += pbuf[i][ch+64]; cn++; }
      else {
        float* pp = pool + ((size_t)(r * N_GRAPHS + cg)) * 128;
        atomicAdd(pp + ch, acc0); atomicAdd(pp + ch + 64, acc1);
        if (lane == 0) atomicAdd(&cnt[r * N_GRAPHS + cg], (float)cn);
        cg = gbuf[i]; acc0 = pbuf[i][ch]; acc1 = pbuf[i][ch+64]; cn = 1;
      }
    }
    float* pp = pool + ((size_t)(r * N_GRAPHS + cg)) * 128;
    atomicAdd(pp + ch, acc0); atomicAdd(pp + ch + 64, acc1);
    if (lane == 0) atomicAdd(&cnt[r * N_GRAPHS + cg], (float)cn);
  }
}

// ---------------- K9: reduce replicas, divide by count ----------------
__global__ void k_final(const float* __restrict__ pool, const float* __restrict__ cnt,
                        float* __restrict__ out) {
  int idx = blockIdx.x * 256 + threadIdx.x;
  if (idx >= N_GRAPHS * 128) return;
  int g = idx >> 7, c = idx & 127;
  float s = 0.f, nn = 0.f;
#pragma unroll
  for (int r = 0; r < NREP; ++r) {
    s  += pool[((size_t)(r * N_GRAPHS + g)) * 128 + c];
    nn += cnt[r * N_GRAPHS + g];
  }
  out[idx] = s / fmaxf(nn, 1.0f);
}

// ---------------- launch ----------------
extern "C" void kernel_launch(void* const* d_in, const int* in_sizes, int n_in,
                              void* d_out, int out_size, void* d_ws, size_t ws_size,
                              hipStream_t stream) {
  const float* x    = (const float*)d_in[0];
  const int*   ei   = (const int*)  d_in[1];
  const float* ea   = (const float*)d_in[2];
  const int*   batch= (const int*)  d_in[3];
  const float* Wl1  = (const float*)d_in[4];
  const float* Wr1  = (const float*)d_in[5];
  const float* We1  = (const float*)d_in[6];
  const float* att1 = (const float*)d_in[7];
  const float* b1   = (const float*)d_in[8];
  const float* g1   = (const float*)d_in[9];
  const float* be1  = (const float*)d_in[10];
  const float* Wl2  = (const float*)d_in[11];
  const float* Wr2  = (const float*)d_in[12];
  const float* We2  = (const float*)d_in[13];
  const float* att2 = (const float*)d_in[14];
  const float* b2   = (const float*)d_in[15];
  const float* g2   = (const float*)d_in[16];
  const float* be2  = (const float*)d_in[17];
  const int* srcp = ei;
  const int* dstp = ei + N_EDGES;

  const int MAXE2 = N_EDGES + 4 * N_NODES;

  char* ws = (char*)d_ws;
  size_t off = 0;
  auto alloc = [&](size_t bytes) {
    char* p = ws + off; off += (bytes + 15) & ~(size_t)15; return p;
  };
  // --- zeroed region start ---
  int*            deg   = (int*)           alloc((size_t)N_NODES * 4);
  float*          easum = (float*)         alloc((size_t)N_NODES * 4);
  int*            cursor= (int*)           alloc((size_t)N_NODES * 4);
  // --- zeroed region end ---
  int*            off2  = (int*)           alloc((size_t)(N_NODES + 1) * 4);
  int*            part  = (int*)           alloc((size_t)256 * 4);
  int*            base  = (int*)           alloc((size_t)257 * 4);
  int*            ssrc  = (int*)           alloc((size_t)MAXE2 * 4);
  float*          sea   = (float*)         alloc((size_t)MAXE2 * 4);
  uint4*          xh16  = (uint4*)         alloc((size_t)N_NODES * 16);
  unsigned*       Wlh   = (unsigned*)      alloc((size_t)4 * 256 * 4);
  unsigned*       h1b   = (unsigned*)      alloc((size_t)N_NODES * 128 * 4);  // bf16 256ch
  unsigned short* xl2b  = (unsigned short*)alloc((size_t)N_NODES * 128 * 2);  // bf16 128ch
  float*          xr2   = (float*)         alloc((size_t)N_NODES * 128 * 4);
  unsigned short* Btp   = (unsigned short*)alloc((size_t)256 * 256 * 2);
  float*          pool  = (float*)         alloc((size_t)NREP * N_GRAPHS * 128 * 4);
  float*          cnt   = (float*)         alloc((size_t)NREP * N_GRAPHS * 4);

  (void)hipMemsetAsync(deg, 0, (char*)off2 - (char*)deg, stream);  // deg, easum, cursor
  (void)hipMemsetAsync(pool, 0, ((char*)cnt + (((size_t)NREP*N_GRAPHS*4 + 15) & ~(size_t)15))
                           - (char*)pool, stream);

  k_hist    <<<N_EDGES / 256, 256, 0, stream>>>(dstp, ea, deg, easum);
  k_prep    <<<SCAN_BLKS + 4 + 256, 256, 0, stream>>>(x, xh16, Wl1, Wlh, Wl2, Wr2, Btp);
  k_scanA   <<<SCAN_BLKS, 256, 0, stream>>>(deg, part);
  k_scanB   <<<1, 256, 0, stream>>>(part, base);
  k_scanC   <<<SCAN_BLKS, 256, 0, stream>>>(deg, base, easum, off2, ssrc, sea);
  k_scatter <<<N_EDGES / 256, 256, 0, stream>>>(srcp, dstp, ea, off2, cursor, ssrc, sea);
  k_gat1    <<<N_NODES / 4, 256, 0, stream>>>(x, xh16, Wlh, Wr1, We1, att1, b1, g1, be1,
                                              off2, ssrc, sea, h1b);
  dim3 g7((N_NODES + 63) / 64, 4);
  k_gemm2   <<<g7, 256, 0, stream>>>(h1b, Btp, xl2b, xr2);
  k_gat2    <<<N_NODES / 4, 256, 0, stream>>>((const unsigned*)xl2b, xr2, We2, att2,
                                              b2, g2, be2,
                                              off2, ssrc, sea, batch, pool, cnt);
  k_final   <<<(N_GRAPHS * 128) / 256, 256, 0, stream>>>(pool, cnt, (float*)d_out);
}

// Round 11
// 415.320 us; speedup vs baseline: 1.5927x; 1.0527x over previous
//
#include <hip/hip_runtime.h>
#include <math.h>

#define N_NODES 50000
#define N_EDGES 800000
#define N_GRAPHS 64
#define NREP 32
#define LN_EPS 1e-5f
#define SCAN_BLKS 196          // ceil(50000/256)

typedef __attribute__((ext_vector_type(8))) short bf16x8;
typedef __attribute__((ext_vector_type(4))) float f32x4;
typedef __attribute__((ext_vector_type(2))) _Float16 half2v;

// ---------------- DPP-based reductions (no LDS latency) ----------------
template <int CTRL>
__device__ __forceinline__ float dppadd(float v) {
  int t = __builtin_amdgcn_update_dpp(0, __float_as_int(v), CTRL, 0xF, 0xF, true);
  return v + __int_as_float(t);
}
__device__ __forceinline__ float red16d(float p) {
  p = dppadd<0xB1>(p);   // quad_perm [1,0,3,2]
  p = dppadd<0x4E>(p);   // quad_perm [2,3,0,1]
  p = dppadd<0x141>(p);  // row_half_mirror
  p = dppadd<0x140>(p);  // row_mirror
  return p;
}
__device__ __forceinline__ float red64(float p) {
  p = red16d(p);
  p += __shfl_xor(p, 16); p += __shfl_xor(p, 32);
  return p;
}

__device__ __forceinline__ unsigned f2bf(float f) {  // rne f32->bf16
  unsigned u = __float_as_uint(f);
  return (u + 0x7fffu + ((u >> 16) & 1u)) >> 16;
}
__device__ __forceinline__ float bflo(unsigned u) { return __uint_as_float(u << 16); }
__device__ __forceinline__ float bfhi(unsigned u) { return __uint_as_float(u & 0xffff0000u); }

__device__ __forceinline__ half2v u2h(unsigned u) {
  return __builtin_bit_cast(half2v, u);
}
__device__ __forceinline__ float dot8h(uint4 xh, unsigned w0, unsigned w1,
                                       unsigned w2, unsigned w3) {
#if __has_builtin(__builtin_amdgcn_fdot2)
  float s = __builtin_amdgcn_fdot2(u2h(xh.x), u2h(w0), 0.f, false);
  s = __builtin_amdgcn_fdot2(u2h(xh.y), u2h(w1), s, false);
  s = __builtin_amdgcn_fdot2(u2h(xh.z), u2h(w2), s, false);
  s = __builtin_amdgcn_fdot2(u2h(xh.w), u2h(w3), s, false);
  return s;
#else
  float s = 0.f;
  half2v a;
  a = u2h(xh.x); { half2v b = u2h(w0); s += (float)a.x*(float)b.x + (float)a.y*(float)b.y; }
  a = u2h(xh.y); { half2v b = u2h(w1); s += (float)a.x*(float)b.x + (float)a.y*(float)b.y; }
  a = u2h(xh.z); { half2v b = u2h(w2); s += (float)a.x*(float)b.x + (float)a.y*(float)b.y; }
  a = u2h(xh.w); { half2v b = u2h(w3); s += (float)a.x*(float)b.x + (float)a.y*(float)b.y; }
  return s;
#endif
}

// ---------------- K1: per-dst degree + edge_attr sum ----------------
__global__ void k_hist(const int* __restrict__ dst, const float* __restrict__ ea,
                       int* __restrict__ deg, float* __restrict__ easum) {
  int e = blockIdx.x * 256 + threadIdx.x;
  if (e >= N_EDGES) return;
  int d = dst[e];
  atomicAdd(&deg[d], 1);
  atomicAdd(&easum[d], ea[e]);
}

// ---------------- K2: multi-block exclusive scan of quad-padded lengths ----------
__global__ void k_scanA(const int* __restrict__ deg, int* __restrict__ part) {
  int t = threadIdx.x;
  int i = blockIdx.x * 256 + t;
  int len = (i < N_NODES) ? ((deg[i] + 4) & ~3) : 0;
  __shared__ int sm[256];
  sm[t] = len; __syncthreads();
  for (int o = 128; o > 0; o >>= 1) {
    if (t < o) sm[t] += sm[t + o];
    __syncthreads();
  }
  if (t == 0) part[blockIdx.x] = sm[0];
}
__global__ void k_scanB(const int* __restrict__ part, int* __restrict__ base) {
  int t = threadIdx.x;                 // 256 threads, 1 block
  __shared__ int sm[256];
  int v = (t < SCAN_BLKS) ? part[t] : 0;
  sm[t] = v; __syncthreads();
  for (int o = 1; o < 256; o <<= 1) {
    int u = (t >= o) ? sm[t - o] : 0;
    __syncthreads();
    sm[t] += u;
    __syncthreads();
  }
  base[t] = (t == 0) ? 0 : sm[t - 1];  // exclusive
}
// scanC fused with self-loop + sentinel-pad writes (packed sent entries)
__global__ void k_scanC(const int* __restrict__ deg, const int* __restrict__ base,
                        const float* __restrict__ easum,
                        int* __restrict__ off2, uint2* __restrict__ sent) {
  int t = threadIdx.x;
  int i = blockIdx.x * 256 + t;
  int d = (i < N_NODES) ? deg[i] : 0;
  int len = (i < N_NODES) ? ((d + 4) & ~3) : 0;
  __shared__ int sm[256];
  sm[t] = len; __syncthreads();
  for (int o = 1; o < 256; o <<= 1) {
    int u = (t >= o) ? sm[t - o] : 0;
    __syncthreads();
    sm[t] += u;
    __syncthreads();
  }
  int incl = sm[t];
  if (i < N_NODES) {
    int b = base[blockIdx.x] + incl - len;
    off2[i] = b;
    float lea = easum[i] / fmaxf((float)d, 1.0f);
    sent[b + d] = make_uint2((unsigned)i, __float_as_uint(lea));
    for (int j = d + 1; j < len; ++j) sent[b + j] = make_uint2(0xFFFFFFFFu, 0u);
  }
  if (i == N_NODES - 1) off2[N_NODES] = base[blockIdx.x] + incl;
}

// ---------------- K4: counting-sort scatter (edges grouped by dst) ----------------
__global__ void k_scatter(const int* __restrict__ src, const int* __restrict__ dst,
                          const float* __restrict__ ea, const int* __restrict__ off2,
                          int* __restrict__ cursor, uint2* __restrict__ sent) {
  int e = blockIdx.x * 256 + threadIdx.x;
  if (e >= N_EDGES) return;
  int d = dst[e];
  int pos = off2[d] + atomicAdd(&cursor[d], 1);
  sent[pos] = make_uint2((unsigned)src[e], __float_as_uint(ea[e]));
}

// ---------------- K5: fused prep (xh16 | Wlh | Btp) ----------------
__global__ void k_prep(const float* __restrict__ x, uint4* __restrict__ xh,
                       const float* __restrict__ Wl1, unsigned* __restrict__ Wlh,
                       const float* __restrict__ Wl2, const float* __restrict__ Wr2,
                       unsigned short* __restrict__ Btp) {
  int b = blockIdx.x, t = threadIdx.x;
  if (b < SCAN_BLKS) {                       // x -> packed f16 pairs
    int n = b * 256 + t;
    if (n >= N_NODES) return;
    float4 a = *(const float4*)(x + n * 8);
    float4 c = *(const float4*)(x + n * 8 + 4);
    half2v p0 = {(_Float16)a.x, (_Float16)a.y};
    half2v p1 = {(_Float16)a.z, (_Float16)a.w};
    half2v p2 = {(_Float16)c.x, (_Float16)c.y};
    half2v p3 = {(_Float16)c.z, (_Float16)c.w};
    xh[n] = make_uint4(__builtin_bit_cast(unsigned, p0), __builtin_bit_cast(unsigned, p1),
                       __builtin_bit_cast(unsigned, p2), __builtin_bit_cast(unsigned, p3));
  } else if (b < SCAN_BLKS + 4) {            // Wl1 -> packed f16 k-pairs
    int kp = b - SCAN_BLKS;
    half2v h = {(_Float16)Wl1[(2 * kp) * 256 + t], (_Float16)Wl1[(2 * kp + 1) * 256 + t]};
    Wlh[kp * 256 + t] = __builtin_bit_cast(unsigned, h);
  } else {                                   // [Wl2|Wr2]^T -> Btp bf16
    int nIdx = b - SCAN_BLKS - 4;            // 0..255
    float v = (nIdx < 128) ? Wl2[t * 128 + nIdx] : Wr2[t * 128 + (nIdx - 128)];
    Btp[nIdx * 256 + t] = (unsigned short)f2bf(v);
  }
}

// ---------------- K6: fused GATv2 layer 1 + bias + LN + ELU -> h1 (bf16) ----------
__global__ __launch_bounds__(256) void k_gat1(
    const float* __restrict__ x, const uint4* __restrict__ xh16,
    const unsigned* __restrict__ Wlh,
    const float* __restrict__ Wr, const float* __restrict__ We,
    const float* __restrict__ att,
    const float* __restrict__ b1, const float* __restrict__ g1,
    const float* __restrict__ be1,
    const int* __restrict__ off2, const uint2* __restrict__ sent,
    unsigned* __restrict__ h1b) {
  int lane = threadIdx.x & 63;
  int wv = __builtin_amdgcn_readfirstlane(threadIdx.x >> 6);
  int n = blockIdx.x * 4 + wv;
  int c0 = lane * 4;

  float4 wev = *(const float4*)(We + c0);
  float4 atv = *(const float4*)(att + c0);

  float xn[8];
  {
    float4 a = *(const float4*)(x + n * 8);
    float4 b = *(const float4*)(x + n * 8 + 4);
    xn[0]=a.x; xn[1]=a.y; xn[2]=a.z; xn[3]=a.w;
    xn[4]=b.x; xn[5]=b.y; xn[6]=b.z; xn[7]=b.w;
  }
  float xr0=0.f, xr1=0.f, xr2=0.f, xr3=0.f;
#pragma unroll
  for (int k = 0; k < 8; ++k) {
    float4 wr = *(const float4*)(Wr + k * 256 + c0);
    xr0 += xn[k]*wr.x; xr1 += xn[k]*wr.y; xr2 += xn[k]*wr.z; xr3 += xn[k]*wr.w;
  }
  uint4 wk0 = *(const uint4*)(Wlh + 0 * 256 + c0);
  uint4 wk1 = *(const uint4*)(Wlh + 1 * 256 + c0);
  uint4 wk2 = *(const uint4*)(Wlh + 2 * 256 + c0);
  uint4 wk3 = *(const uint4*)(Wlh + 3 * 256 + c0);

  int beg   = __builtin_amdgcn_readfirstlane(off2[n]);
  int pairs = __builtin_amdgcn_readfirstlane((off2[n + 1] - beg) >> 1);

  float den = 0.f, ac0=0.f, ac1=0.f, ac2=0.f, ac3=0.f;

  // prefetch pair 0 as one 16B packed load: {sA, eA, sB, eB}
  uint4 pr = *(const uint4*)(sent + beg);
  int   sA = __builtin_amdgcn_readfirstlane((int)pr.x);
  int   sB = __builtin_amdgcn_readfirstlane((int)pr.z);
  float eA = __uint_as_float(pr.y), eB = __uint_as_float(pr.w);
  uint4 xA = xh16[max(sA, 0)];
  uint4 xB = xh16[max(sB, 0)];

  for (int p = 0; p < pairs; ++p) {
    int   csA = sA, csB = sB;
    float ceA = eA, ceB = eB;
    uint4 cxA = xA, cxB = xB;
    if (p + 1 < pairs) {
      pr = *(const uint4*)(sent + beg + 2 * (p + 1));
      sA = __builtin_amdgcn_readfirstlane((int)pr.x);
      sB = __builtin_amdgcn_readfirstlane((int)pr.z);
      eA = __uint_as_float(pr.y); eB = __uint_as_float(pr.w);
      xA = xh16[max(sA, 0)];
      xB = xh16[max(sB, 0)];
    }
    float vA0 = dot8h(cxA, wk0.x, wk1.x, wk2.x, wk3.x);
    float vA1 = dot8h(cxA, wk0.y, wk1.y, wk2.y, wk3.y);
    float vA2 = dot8h(cxA, wk0.z, wk1.z, wk2.z, wk3.z);
    float vA3 = dot8h(cxA, wk0.w, wk1.w, wk2.w, wk3.w);
    float vB0 = dot8h(cxB, wk0.x, wk1.x, wk2.x, wk3.x);
    float vB1 = dot8h(cxB, wk0.y, wk1.y, wk2.y, wk3.y);
    float vB2 = dot8h(cxB, wk0.z, wk1.z, wk2.z, wk3.z);
    float vB3 = dot8h(cxB, wk0.w, wk1.w, wk2.w, wk3.w);

    float mA0 = vA0 + fmaf(ceA, wev.x, xr0); mA0 = fmaxf(mA0, 0.2f*mA0);
    float mA1 = vA1 + fmaf(ceA, wev.y, xr1); mA1 = fmaxf(mA1, 0.2f*mA1);
    float mA2 = vA2 + fmaf(ceA, wev.z, xr2); mA2 = fmaxf(mA2, 0.2f*mA2);
    float mA3 = vA3 + fmaf(ceA, wev.w, xr3); mA3 = fmaxf(mA3, 0.2f*mA3);
    float mB0 = vB0 + fmaf(ceB, wev.x, xr0); mB0 = fmaxf(mB0, 0.2f*mB0);
    float mB1 = vB1 + fmaf(ceB, wev.y, xr1); mB1 = fmaxf(mB1, 0.2f*mB1);
    float mB2 = vB2 + fmaf(ceB, wev.z, xr2); mB2 = fmaxf(mB2, 0.2f*mB2);
    float mB3 = vB3 + fmaf(ceB, wev.w, xr3); mB3 = fmaxf(mB3, 0.2f*mB3);

    float pA = mA0*atv.x + mA1*atv.y + mA2*atv.z + mA3*atv.w;
    float pB = mB0*atv.x + mB1*atv.y + mB2*atv.z + mB3*atv.w;
    pA = red16d(pA);
    pB = red16d(pB);

    float wA = (csA >= 0) ? __expf(pA) : 0.f;
    float wB = (csB >= 0) ? __expf(pB) : 0.f;
    den += wA + wB;
    ac0 = fmaf(wA, vA0, fmaf(wB, vB0, ac0));
    ac1 = fmaf(wA, vA1, fmaf(wB, vB1, ac1));
    ac2 = fmaf(wA, vA2, fmaf(wB, vB2, ac2));
    ac3 = fmaf(wA, vA3, fmaf(wB, vB3, ac3));
  }

  float inv = 1.0f / (den + 1e-16f);
  float4 bv = *(const float4*)(b1 + c0);
  float o0 = ac0*inv + bv.x, o1 = ac1*inv + bv.y;
  float o2 = ac2*inv + bv.z, o3 = ac3*inv + bv.w;
  float mu = red64(o0 + o1 + o2 + o3) * (1.0f / 256.0f);
  float d0 = o0-mu, d1 = o1-mu, d2 = o2-mu, d3 = o3-mu;
  float rstd = rsqrtf(red64(d0*d0 + d1*d1 + d2*d2 + d3*d3) * (1.0f/256.0f) + LN_EPS);
  float4 gv  = *(const float4*)(g1 + c0);
  float4 bev = *(const float4*)(be1 + c0);
  float y0 = d0*rstd*gv.x + bev.x; y0 = y0 > 0.f ? y0 : __expf(y0) - 1.0f;
  float y1 = d1*rstd*gv.y + bev.y; y1 = y1 > 0.f ? y1 : __expf(y1) - 1.0f;
  float y2 = d2*rstd*gv.z + bev.z; y2 = y2 > 0.f ? y2 : __expf(y2) - 1.0f;
  float y3 = d3*rstd*gv.w + bev.w; y3 = y3 > 0.f ? y3 : __expf(y3) - 1.0f;
  unsigned lo = f2bf(y0) | (f2bf(y1) << 16);
  unsigned hi = f2bf(y2) | (f2bf(y3) << 16);
  *(uint2*)(h1b + (size_t)n * 128 + lane * 2) = make_uint2(lo, hi);
}

// ---------------- K7: MFMA GEMM  [xl2|xr2] = h1(bf16) @ Btp^T ----------------
// A (64 nodes x K256) staged ONCE; loop 4 B-panels of 64 cols each.
__global__ __launch_bounds__(256) void k_gemm2(
    const unsigned* __restrict__ h1b, const unsigned short* __restrict__ Btp,
    unsigned short* __restrict__ xl2b, float* __restrict__ xr2) {
  __shared__ unsigned short Ash[64][264];
  __shared__ unsigned short Bsh[64][264];
  int t = threadIdx.x;
  int bm0 = blockIdx.x * 64;
  int lane = t & 63, w = t >> 6;
  int lm = lane & 15, lk = (lane >> 4) * 8;

  // stage A: 64 rows x 256 bf16 = 2048 uint4
#pragma unroll
  for (int i = 0; i < 8; ++i) {
    int idx = t + 256 * i;
    int row = idx >> 5, c4 = idx & 31;
    int gm = bm0 + row;
    uint4 va = (gm < N_NODES) ? *(const uint4*)(h1b + (size_t)gm * 128 + c4 * 4)
                              : make_uint4(0,0,0,0);
    *(uint4*)(&Ash[row][c4 * 8]) = va;
  }

  for (int pnl = 0; pnl < 4; ++pnl) {
    int n0 = pnl * 64;
    // stage B panel: 64 cols x 256 bf16
#pragma unroll
    for (int i = 0; i < 8; ++i) {
      int idx = t + 256 * i;
      int row = idx >> 5, c4 = idx & 31;
      uint4 vb = *(const uint4*)((const unsigned*)Btp + (size_t)(n0 + row) * 128 + c4 * 4);
      *(uint4*)(&Bsh[row][c4 * 8]) = vb;
    }
    __syncthreads();

    f32x4 acc[4];
#pragma unroll
    for (int i = 0; i < 4; ++i) acc[i] = (f32x4){0.f,0.f,0.f,0.f};
#pragma unroll
    for (int kk = 0; kk < 8; ++kk) {
      bf16x8 a = *(const bf16x8*)(&Ash[16*w + lm][kk*32 + lk]);
#pragma unroll
      for (int tt = 0; tt < 4; ++tt) {
        bf16x8 b = *(const bf16x8*)(&Bsh[16*tt + lm][kk*32 + lk]);
        acc[tt] = __builtin_amdgcn_mfma_f32_16x16x32_bf16(a, b, acc[tt], 0, 0, 0);
      }
    }

#pragma unroll
    for (int tt = 0; tt < 4; ++tt) {
#pragma unroll
      for (int r = 0; r < 4; ++r) {
        int node = bm0 + 16*w + (lane >> 4) * 4 + r;
        if (node < N_NODES) {
          int colg = n0 + tt * 16 + lm;
          float v = acc[tt][r];
          if (colg < 128) xl2b[(size_t)node * 128 + colg] = (unsigned short)f2bf(v);
          else            xr2 [(size_t)node * 128 + (colg - 128)] = v;
        }
      }
    }
    __syncthreads();   // before overwriting Bsh next panel
  }
}

// ---------------- K8: fused GATv2 layer 2 + bias + LN + ELU + pooled atomics ------
__global__ __launch_bounds__(256) void k_gat2(
    const unsigned* __restrict__ xl2b, const float* __restrict__ xr2,
    const float* __restrict__ We, const float* __restrict__ att,
    const float* __restrict__ b2, const float* __restrict__ g2,
    const float* __restrict__ be2,
    const int* __restrict__ off2, const uint2* __restrict__ sent,
    const int* __restrict__ batch,
    float* __restrict__ pool, float* __restrict__ cnt) {
  int tid = threadIdx.x;
  int lane = tid & 63;
  int wv = __builtin_amdgcn_readfirstlane(tid >> 6);
  int row = lane >> 4, col = lane & 15;
  int n = blockIdx.x * 4 + wv;
  int c0 = col * 8;               // 8 channels per lane
  int cu0 = col * 4;              // uint offset into bf16-packed row

  float wev[8], at[8], xr[8];
  *(float4*)(wev)     = *(const float4*)(We + c0);
  *(float4*)(wev + 4) = *(const float4*)(We + c0 + 4);
  *(float4*)(at)      = *(const float4*)(att + c0);
  *(float4*)(at + 4)  = *(const float4*)(att + c0 + 4);
  *(float4*)(xr)      = *(const float4*)(xr2 + (size_t)n * 128 + c0);
  *(float4*)(xr + 4)  = *(const float4*)(xr2 + (size_t)n * 128 + c0 + 4);

  int beg   = __builtin_amdgcn_readfirstlane(off2[n]);
  int quads = __builtin_amdgcn_readfirstlane((off2[n + 1] - beg) >> 2);  // >= 1

  float den = 0.f;
  float ac[8] = {0,0,0,0,0,0,0,0};

  // depth-3 pipeline; each row of 16 lanes owns one edge per quad
  int s0 = -1, s1 = -1, s2 = -1;
  float e0 = 0.f, e1 = 0.f, e2 = 0.f;
  uint4 u0 = make_uint4(0,0,0,0), u1 = u0, u2 = u0;
  {
    uint2 tt = sent[beg + row];
    s0 = (int)tt.x; e0 = __uint_as_float(tt.y);
    u0 = *(const uint4*)(xl2b + (size_t)max(s0, 0) * 64 + cu0);
  }
  if (quads > 1) {
    uint2 tt = sent[beg + 4 + row];
    s1 = (int)tt.x; e1 = __uint_as_float(tt.y);
    u1 = *(const uint4*)(xl2b + (size_t)max(s1, 0) * 64 + cu0);
  }
  if (quads > 2) {
    uint2 tt = sent[beg + 8 + row];
    s2 = (int)tt.x; e2 = __uint_as_float(tt.y);
    u2 = *(const uint4*)(xl2b + (size_t)max(s2, 0) * 64 + cu0);
  }

  for (int q = 0; q < quads; ++q) {
    int cs = s0; float ce = e0; uint4 cu = u0;
    s0 = s1; e0 = e1; u0 = u1;
    s1 = s2; e1 = e2; u1 = u2;
    if (q + 3 < quads) {
      uint2 tt = sent[beg + (q + 3) * 4 + row];
      s2 = (int)tt.x; e2 = __uint_as_float(tt.y);
      u2 = *(const uint4*)(xl2b + (size_t)max(s2, 0) * 64 + cu0);
    }
    float v[8];
    v[0]=bflo(cu.x); v[1]=bfhi(cu.x); v[2]=bflo(cu.y); v[3]=bfhi(cu.y);
    v[4]=bflo(cu.z); v[5]=bfhi(cu.z); v[6]=bflo(cu.w); v[7]=bfhi(cu.w);
    float p = 0.f;
#pragma unroll
    for (int j = 0; j < 8; ++j) {
      float m = v[j] + fmaf(ce, wev[j], xr[j]);
      m = fmaxf(m, 0.2f * m);
      p = fmaf(m, at[j], p);
    }
    p = red16d(p);
    float w = (cs >= 0) ? __expf(p) : 0.f;
    den += w;
#pragma unroll
    for (int j = 0; j < 8; ++j) ac[j] = fmaf(w, v[j], ac[j]);
  }
  den += __shfl_xor(den, 16); den += __shfl_xor(den, 32);
#pragma unroll
  for (int j = 0; j < 8; ++j) {
    ac[j] += __shfl_xor(ac[j], 16);
    ac[j] += __shfl_xor(ac[j], 32);
  }

  float inv = 1.0f / (den + 1e-16f);
  float o[8], y[8];
  float bv[8], gv[8], bev[8];
  *(float4*)(bv)      = *(const float4*)(b2 + c0);
  *(float4*)(bv + 4)  = *(const float4*)(b2 + c0 + 4);
  *(float4*)(gv)      = *(const float4*)(g2 + c0);
  *(float4*)(gv + 4)  = *(const float4*)(g2 + c0 + 4);
  *(float4*)(bev)     = *(const float4*)(be2 + c0);
  *(float4*)(bev + 4) = *(const float4*)(be2 + c0 + 4);
  float osum = 0.f;
#pragma unroll
  for (int j = 0; j < 8; ++j) { o[j] = ac[j] * inv + bv[j]; osum += o[j]; }
  float mu = red64(osum) * (1.0f / 512.0f);
  float vsum = 0.f;
#pragma unroll
  for (int j = 0; j < 8; ++j) { o[j] -= mu; vsum += o[j] * o[j]; }
  float rstd = rsqrtf(red64(vsum) * (1.0f / 512.0f) + LN_EPS);
#pragma unroll
  for (int j = 0; j < 8; ++j) {
    float t2 = o[j] * rstd * gv[j] + bev[j];
    y[j] = t2 > 0.f ? t2 : __expf(t2) - 1.0f;
  }

  // block-level pool dedup (batch sorted -> usually 1 graph per block)
  __shared__ float pbuf[4][128];
  __shared__ int gbuf[4];
  if (row == 0) {
#pragma unroll
    for (int j = 0; j < 8; ++j) pbuf[wv][c0 + j] = y[j];
  }
  if (lane == 0) gbuf[wv] = batch[n];
  __syncthreads();
  if (wv == 0) {
    int r = blockIdx.x & (NREP - 1);
    int ch = lane;                       // handles ch and ch+64
    float acc0 = pbuf[0][ch], acc1 = pbuf[0][ch+64];
    int cg = gbuf[0], cn = 1;
#pragma unroll
    for (int i = 1; i < 4; ++i) {
      if (gbuf[i] == cg) { acc0 += pbuf[i][ch]; acc1 += pbuf[i][ch+64]; cn++; }
      else {
        float* pp = pool + ((size_t)(r * N_GRAPHS + cg)) * 128;
        atomicAdd(pp + ch, acc0); atomicAdd(pp + ch + 64, acc1);
        if (lane == 0) atomicAdd(&cnt[r * N_GRAPHS + cg], (float)cn);
        cg = gbuf[i]; acc0 = pbuf[i][ch]; acc1 = pbuf[i][ch+64]; cn = 1;
      }
    }
    float* pp = pool + ((size_t)(r * N_GRAPHS + cg)) * 128;
    atomicAdd(pp + ch, acc0); atomicAdd(pp + ch + 64, acc1);
    if (lane == 0) atomicAdd(&cnt[r * N_GRAPHS + cg], (float)cn);
  }
}

// ---------------- K9: reduce replicas, divide by count ----------------
__global__ void k_final(const float* __restrict__ pool, const float* __restrict__ cnt,
                        float* __restrict__ out) {
  int idx = blockIdx.x * 256 + threadIdx.x;
  if (idx >= N_GRAPHS * 128) return;
  int g = idx >> 7, c = idx & 127;
  float s = 0.f, nn = 0.f;
#pragma unroll
  for (int r = 0; r < NREP; ++r) {
    s  += pool[((size_t)(r * N_GRAPHS + g)) * 128 + c];
    nn += cnt[r * N_GRAPHS + g];
  }
  out[idx] = s / fmaxf(nn, 1.0f);
}

// ---------------- launch ----------------
extern "C" void kernel_launch(void* const* d_in, const int* in_sizes, int n_in,
                              void* d_out, int out_size, void* d_ws, size_t ws_size,
                              hipStream_t stream) {
  const float* x    = (const float*)d_in[0];
  const int*   ei   = (const int*)  d_in[1];
  const float* ea   = (const float*)d_in[2];
  const int*   batch= (const int*)  d_in[3];
  const float* Wl1  = (const float*)d_in[4];
  const float* Wr1  = (const float*)d_in[5];
  const float* We1  = (const float*)d_in[6];
  const float* att1 = (const float*)d_in[7];
  const float* b1   = (const float*)d_in[8];
  const float* g1   = (const float*)d_in[9];
  const float* be1  = (const float*)d_in[10];
  const float* Wl2  = (const float*)d_in[11];
  const float* Wr2  = (const float*)d_in[12];
  const float* We2  = (const float*)d_in[13];
  const float* att2 = (const float*)d_in[14];
  const float* b2   = (const float*)d_in[15];
  const float* g2   = (const float*)d_in[16];
  const float* be2  = (const float*)d_in[17];
  const int* srcp = ei;
  const int* dstp = ei + N_EDGES;

  const int MAXE2 = N_EDGES + 4 * N_NODES;

  char* ws = (char*)d_ws;
  size_t off = 0;
  auto alloc = [&](size_t bytes) {
    char* p = ws + off; off += (bytes + 15) & ~(size_t)15; return p;
  };
  // --- zeroed region start ---
  int*            deg   = (int*)           alloc((size_t)N_NODES * 4);
  float*          easum = (float*)         alloc((size_t)N_NODES * 4);
  int*            cursor= (int*)           alloc((size_t)N_NODES * 4);
  // --- zeroed region end ---
  int*            off2  = (int*)           alloc((size_t)(N_NODES + 1) * 4);
  int*            part  = (int*)           alloc((size_t)256 * 4);
  int*            base  = (int*)           alloc((size_t)257 * 4);
  uint2*          sent  = (uint2*)         alloc((size_t)MAXE2 * 8);
  uint4*          xh16  = (uint4*)         alloc((size_t)N_NODES * 16);
  unsigned*       Wlh   = (unsigned*)      alloc((size_t)4 * 256 * 4);
  unsigned*       h1b   = (unsigned*)      alloc((size_t)N_NODES * 128 * 4);  // bf16 256ch
  unsigned short* xl2b  = (unsigned short*)alloc((size_t)N_NODES * 128 * 2);  // bf16 128ch
  float*          xr2   = (float*)         alloc((size_t)N_NODES * 128 * 4);
  unsigned short* Btp   = (unsigned short*)alloc((size_t)256 * 256 * 2);
  float*          pool  = (float*)         alloc((size_t)NREP * N_GRAPHS * 128 * 4);
  float*          cnt   = (float*)         alloc((size_t)NREP * N_GRAPHS * 4);

  (void)hipMemsetAsync(deg, 0, (char*)off2 - (char*)deg, stream);  // deg, easum, cursor
  (void)hipMemsetAsync(pool, 0, ((char*)cnt + (((size_t)NREP*N_GRAPHS*4 + 15) & ~(size_t)15))
                           - (char*)pool, stream);

  k_hist    <<<N_EDGES / 256, 256, 0, stream>>>(dstp, ea, deg, easum);
  k_prep    <<<SCAN_BLKS + 4 + 256, 256, 0, stream>>>(x, xh16, Wl1, Wlh, Wl2, Wr2, Btp);
  k_scanA   <<<SCAN_BLKS, 256, 0, stream>>>(deg, part);
  k_scanB   <<<1, 256, 0, stream>>>(part, base);
  k_scanC   <<<SCAN_BLKS, 256, 0, stream>>>(deg, base, easum, off2, sent);
  k_scatter <<<N_EDGES / 256, 256, 0, stream>>>(srcp, dstp, ea, off2, cursor, sent);
  k_gat1    <<<N_NODES / 4, 256, 0, stream>>>(x, xh16, Wlh, Wr1, We1, att1, b1, g1, be1,
                                              off2, sent, h1b);
  k_gemm2   <<<(N_NODES + 63) / 64, 256, 0, stream>>>(h1b, Btp, xl2b, xr2);
  k_gat2    <<<N_NODES / 4, 256, 0, stream>>>((const unsigned*)xl2b, xr2, We2, att2,
                                              b2, g2, be2,
                                              off2, sent, batch, pool, cnt);
  k_final   <<<(N_GRAPHS * 128) / 256, 256, 0, stream>>>(pool, cnt, (float*)d_out);
}

// Round 13
// 395.548 us; speedup vs baseline: 1.6723x; 1.0500x over previous
//
#include <hip/hip_runtime.h>
#include <math.h>

#define N_NODES 50000
#define N_EDGES 800000
#define N_GRAPHS 64
#define NREP 32
#define LN_EPS 1e-5f
#define SCAN_BLKS 196          // ceil(50000/256)

typedef __attribute__((ext_vector_type(8))) short bf16x8;
typedef __attribute__((ext_vector_type(4))) float f32x4;
typedef __attribute__((ext_vector_type(2))) _Float16 half2v;

// ---------------- DPP-based reductions (no LDS latency) ----------------
template <int CTRL>
__device__ __forceinline__ float dppadd(float v) {
  int t = __builtin_amdgcn_update_dpp(0, __float_as_int(v), CTRL, 0xF, 0xF, true);
  return v + __int_as_float(t);
}
__device__ __forceinline__ float red16d(float p) {
  p = dppadd<0xB1>(p);   // quad_perm [1,0,3,2]
  p = dppadd<0x4E>(p);   // quad_perm [2,3,0,1]
  p = dppadd<0x141>(p);  // row_half_mirror
  p = dppadd<0x140>(p);  // row_mirror
  return p;
}
__device__ __forceinline__ float red64(float p) {
  p = red16d(p);
  p += __shfl_xor(p, 16); p += __shfl_xor(p, 32);
  return p;
}

__device__ __forceinline__ unsigned f2bf(float f) {  // rne f32->bf16
  unsigned u = __float_as_uint(f);
  return (u + 0x7fffu + ((u >> 16) & 1u)) >> 16;
}
__device__ __forceinline__ float bflo(unsigned u) { return __uint_as_float(u << 16); }
__device__ __forceinline__ float bfhi(unsigned u) { return __uint_as_float(u & 0xffff0000u); }

__device__ __forceinline__ half2v u2h(unsigned u) {
  return __builtin_bit_cast(half2v, u);
}
__device__ __forceinline__ float dot8h(uint4 xh, unsigned w0, unsigned w1,
                                       unsigned w2, unsigned w3) {
#if __has_builtin(__builtin_amdgcn_fdot2)
  float s = __builtin_amdgcn_fdot2(u2h(xh.x), u2h(w0), 0.f, false);
  s = __builtin_amdgcn_fdot2(u2h(xh.y), u2h(w1), s, false);
  s = __builtin_amdgcn_fdot2(u2h(xh.z), u2h(w2), s, false);
  s = __builtin_amdgcn_fdot2(u2h(xh.w), u2h(w3), s, false);
  return s;
#else
  float s = 0.f;
  half2v a;
  a = u2h(xh.x); { half2v b = u2h(w0); s += (float)a.x*(float)b.x + (float)a.y*(float)b.y; }
  a = u2h(xh.y); { half2v b = u2h(w1); s += (float)a.x*(float)b.x + (float)a.y*(float)b.y; }
  a = u2h(xh.z); { half2v b = u2h(w2); s += (float)a.x*(float)b.x + (float)a.y*(float)b.y; }
  a = u2h(xh.w); { half2v b = u2h(w3); s += (float)a.x*(float)b.x + (float)a.y*(float)b.y; }
  return s;
#endif
}

// ---------------- K1: per-dst degree + edge_attr sum + edge rank ----------------
__global__ void k_hist(const int* __restrict__ dst, const float* __restrict__ ea,
                       int* __restrict__ deg, float* __restrict__ easum,
                       int* __restrict__ erank) {
  int e = blockIdx.x * 256 + threadIdx.x;
  if (e >= N_EDGES) return;
  int d = dst[e];
  erank[e] = atomicAdd(&deg[d], 1);   // rank within destination segment
  atomicAdd(&easum[d], ea[e]);
}

// ---------------- K2: multi-block exclusive scan of quad-padded lengths ----------
__global__ void k_scanA(const int* __restrict__ deg, int* __restrict__ part) {
  int t = threadIdx.x;
  int i = blockIdx.x * 256 + t;
  int len = (i < N_NODES) ? ((deg[i] + 4) & ~3) : 0;
  __shared__ int sm[256];
  sm[t] = len; __syncthreads();
  for (int o = 128; o > 0; o >>= 1) {
    if (t < o) sm[t] += sm[t + o];
    __syncthreads();
  }
  if (t == 0) part[blockIdx.x] = sm[0];
}
__global__ void k_scanB(const int* __restrict__ part, int* __restrict__ base) {
  int t = threadIdx.x;                 // 256 threads, 1 block
  __shared__ int sm[256];
  int v = (t < SCAN_BLKS) ? part[t] : 0;
  sm[t] = v; __syncthreads();
  for (int o = 1; o < 256; o <<= 1) {
    int u = (t >= o) ? sm[t - o] : 0;
    __syncthreads();
    sm[t] += u;
    __syncthreads();
  }
  base[t] = (t == 0) ? 0 : sm[t - 1];  // exclusive
}
// scanC fused with self-loop + sentinel-pad writes (packed sent entries)
__global__ void k_scanC(const int* __restrict__ deg, const int* __restrict__ base,
                        const float* __restrict__ easum,
                        int* __restrict__ off2, uint2* __restrict__ sent) {
  int t = threadIdx.x;
  int i = blockIdx.x * 256 + t;
  int d = (i < N_NODES) ? deg[i] : 0;
  int len = (i < N_NODES) ? ((d + 4) & ~3) : 0;
  __shared__ int sm[256];
  sm[t] = len; __syncthreads();
  for (int o = 1; o < 256; o <<= 1) {
    int u = (t >= o) ? sm[t - o] : 0;
    __syncthreads();
    sm[t] += u;
    __syncthreads();
  }
  int incl = sm[t];
  if (i < N_NODES) {
    int b = base[blockIdx.x] + incl - len;
    off2[i] = b;
    float lea = easum[i] / fmaxf((float)d, 1.0f);
    sent[b + d] = make_uint2((unsigned)i, __float_as_uint(lea));
    for (int j = d + 1; j < len; ++j) sent[b + j] = make_uint2(0xFFFFFFFFu, 0u);
  }
  if (i == N_NODES - 1) off2[N_NODES] = base[blockIdx.x] + incl;
}

// ---------------- K4: scatter via precomputed rank (no atomics) ----------------
__global__ void k_scatter(const int* __restrict__ src, const int* __restrict__ dst,
                          const float* __restrict__ ea, const int* __restrict__ off2,
                          const int* __restrict__ erank, uint2* __restrict__ sent) {
  int e = blockIdx.x * 256 + threadIdx.x;
  if (e >= N_EDGES) return;
  int d = dst[e];
  int pos = off2[d] + erank[e];
  sent[pos] = make_uint2((unsigned)src[e], __float_as_uint(ea[e]));
}

// ---------------- K5: fused prep (xh16 | Wlh | Btp) ----------------
__global__ void k_prep(const float* __restrict__ x, uint4* __restrict__ xh,
                       const float* __restrict__ Wl1, unsigned* __restrict__ Wlh,
                       const float* __restrict__ Wl2, const float* __restrict__ Wr2,
                       unsigned short* __restrict__ Btp) {
  int b = blockIdx.x, t = threadIdx.x;
  if (b < SCAN_BLKS) {                       // x -> packed f16 pairs
    int n = b * 256 + t;
    if (n >= N_NODES) return;
    float4 a = *(const float4*)(x + n * 8);
    float4 c = *(const float4*)(x + n * 8 + 4);
    half2v p0 = {(_Float16)a.x, (_Float16)a.y};
    half2v p1 = {(_Float16)a.z, (_Float16)a.w};
    half2v p2 = {(_Float16)c.x, (_Float16)c.y};
    half2v p3 = {(_Float16)c.z, (_Float16)c.w};
    xh[n] = make_uint4(__builtin_bit_cast(unsigned, p0), __builtin_bit_cast(unsigned, p1),
                       __builtin_bit_cast(unsigned, p2), __builtin_bit_cast(unsigned, p3));
  } else if (b < SCAN_BLKS + 4) {            // Wl1 -> packed f16 k-pairs
    int kp = b - SCAN_BLKS;
    half2v h = {(_Float16)Wl1[(2 * kp) * 256 + t], (_Float16)Wl1[(2 * kp + 1) * 256 + t]};
    Wlh[kp * 256 + t] = __builtin_bit_cast(unsigned, h);
  } else {                                   // [Wl2|Wr2]^T -> Btp bf16
    int nIdx = b - SCAN_BLKS - 4;            // 0..255
    float v = (nIdx < 128) ? Wl2[t * 128 + nIdx] : Wr2[t * 128 + (nIdx - 128)];
    Btp[nIdx * 256 + t] = (unsigned short)f2bf(v);
  }
}

// ---------------- K6: fused GATv2 layer 1 + bias + LN + ELU -> h1 (bf16) ----------
__global__ __launch_bounds__(256) void k_gat1(
    const float* __restrict__ x, const uint4* __restrict__ xh16,
    const unsigned* __restrict__ Wlh,
    const float* __restrict__ Wr, const float* __restrict__ We,
    const float* __restrict__ att,
    const float* __restrict__ b1, const float* __restrict__ g1,
    const float* __restrict__ be1,
    const int* __restrict__ off2, const uint2* __restrict__ sent,
    unsigned* __restrict__ h1b) {
  int lane = threadIdx.x & 63;
  int wv = __builtin_amdgcn_readfirstlane(threadIdx.x >> 6);
  int n = blockIdx.x * 4 + wv;
  int c0 = lane * 4;

  float4 wev = *(const float4*)(We + c0);
  float4 atv = *(const float4*)(att + c0);

  float xn[8];
  {
    float4 a = *(const float4*)(x + n * 8);
    float4 b = *(const float4*)(x + n * 8 + 4);
    xn[0]=a.x; xn[1]=a.y; xn[2]=a.z; xn[3]=a.w;
    xn[4]=b.x; xn[5]=b.y; xn[6]=b.z; xn[7]=b.w;
  }
  float xr0=0.f, xr1=0.f, xr2=0.f, xr3=0.f;
#pragma unroll
  for (int k = 0; k < 8; ++k) {
    float4 wr = *(const float4*)(Wr + k * 256 + c0);
    xr0 += xn[k]*wr.x; xr1 += xn[k]*wr.y; xr2 += xn[k]*wr.z; xr3 += xn[k]*wr.w;
  }
  uint4 wk0 = *(const uint4*)(Wlh + 0 * 256 + c0);
  uint4 wk1 = *(const uint4*)(Wlh + 1 * 256 + c0);
  uint4 wk2 = *(const uint4*)(Wlh + 2 * 256 + c0);
  uint4 wk3 = *(const uint4*)(Wlh + 3 * 256 + c0);

  int beg   = __builtin_amdgcn_readfirstlane(off2[n]);
  int pairs = __builtin_amdgcn_readfirstlane((off2[n + 1] - beg) >> 1);

  float den = 0.f, ac0=0.f, ac1=0.f, ac2=0.f, ac3=0.f;

  // prefetch pair 0 as one 16B packed load: {sA, eA, sB, eB}
  uint4 pr = *(const uint4*)(sent + beg);
  int   sA = __builtin_amdgcn_readfirstlane((int)pr.x);
  int   sB = __builtin_amdgcn_readfirstlane((int)pr.z);
  float eA = __uint_as_float(pr.y), eB = __uint_as_float(pr.w);
  uint4 xA = xh16[max(sA, 0)];
  uint4 xB = xh16[max(sB, 0)];

  for (int p = 0; p < pairs; ++p) {
    int   csA = sA, csB = sB;
    float ceA = eA, ceB = eB;
    uint4 cxA = xA, cxB = xB;
    if (p + 1 < pairs) {
      pr = *(const uint4*)(sent + beg + 2 * (p + 1));
      sA = __builtin_amdgcn_readfirstlane((int)pr.x);
      sB = __builtin_amdgcn_readfirstlane((int)pr.z);
      eA = __uint_as_float(pr.y); eB = __uint_as_float(pr.w);
      xA = xh16[max(sA, 0)];
      xB = xh16[max(sB, 0)];
    }
    float vA0 = dot8h(cxA, wk0.x, wk1.x, wk2.x, wk3.x);
    float vA1 = dot8h(cxA, wk0.y, wk1.y, wk2.y, wk3.y);
    float vA2 = dot8h(cxA, wk0.z, wk1.z, wk2.z, wk3.z);
    float vA3 = dot8h(cxA, wk0.w, wk1.w, wk2.w, wk3.w);
    float vB0 = dot8h(cxB, wk0.x, wk1.x, wk2.x, wk3.x);
    float vB1 = dot8h(cxB, wk0.y, wk1.y, wk2.y, wk3.y);
    float vB2 = dot8h(cxB, wk0.z, wk1.z, wk2.z, wk3.z);
    float vB3 = dot8h(cxB, wk0.w, wk1.w, wk2.w, wk3.w);

    float mA0 = vA0 + fmaf(ceA, wev.x, xr0); mA0 = fmaxf(mA0, 0.2f*mA0);
    float mA1 = vA1 + fmaf(ceA, wev.y, xr1); mA1 = fmaxf(mA1, 0.2f*mA1);
    float mA2 = vA2 + fmaf(ceA, wev.z, xr2); mA2 = fmaxf(mA2, 0.2f*mA2);
    float mA3 = vA3 + fmaf(ceA, wev.w, xr3); mA3 = fmaxf(mA3, 0.2f*mA3);
    float mB0 = vB0 + fmaf(ceB, wev.x, xr0); mB0 = fmaxf(mB0, 0.2f*mB0);
    float mB1 = vB1 + fmaf(ceB, wev.y, xr1); mB1 = fmaxf(mB1, 0.2f*mB1);
    float mB2 = vB2 + fmaf(ceB, wev.z, xr2); mB2 = fmaxf(mB2, 0.2f*mB2);
    float mB3 = vB3 + fmaf(ceB, wev.w, xr3); mB3 = fmaxf(mB3, 0.2f*mB3);

    float pA = mA0*atv.x + mA1*atv.y + mA2*atv.z + mA3*atv.w;
    float pB = mB0*atv.x + mB1*atv.y + mB2*atv.z + mB3*atv.w;
    pA = red16d(pA);
    pB = red16d(pB);

    float wA = (csA >= 0) ? __expf(pA) : 0.f;
    float wB = (csB >= 0) ? __expf(pB) : 0.f;
    den += wA + wB;
    ac0 = fmaf(wA, vA0, fmaf(wB, vB0, ac0));
    ac1 = fmaf(wA, vA1, fmaf(wB, vB1, ac1));
    ac2 = fmaf(wA, vA2, fmaf(wB, vB2, ac2));
    ac3 = fmaf(wA, vA3, fmaf(wB, vB3, ac3));
  }

  float inv = 1.0f / (den + 1e-16f);
  float4 bv = *(const float4*)(b1 + c0);
  float o0 = ac0*inv + bv.x, o1 = ac1*inv + bv.y;
  float o2 = ac2*inv + bv.z, o3 = ac3*inv + bv.w;
  float mu = red64(o0 + o1 + o2 + o3) * (1.0f / 256.0f);
  float d0 = o0-mu, d1 = o1-mu, d2 = o2-mu, d3 = o3-mu;
  float rstd = rsqrtf(red64(d0*d0 + d1*d1 + d2*d2 + d3*d3) * (1.0f/256.0f) + LN_EPS);
  float4 gv  = *(const float4*)(g1 + c0);
  float4 bev = *(const float4*)(be1 + c0);
  float y0 = d0*rstd*gv.x + bev.x; y0 = y0 > 0.f ? y0 : __expf(y0) - 1.0f;
  float y1 = d1*rstd*gv.y + bev.y; y1 = y1 > 0.f ? y1 : __expf(y1) - 1.0f;
  float y2 = d2*rstd*gv.z + bev.z; y2 = y2 > 0.f ? y2 : __expf(y2) - 1.0f;
  float y3 = d3*rstd*gv.w + bev.w; y3 = y3 > 0.f ? y3 : __expf(y3) - 1.0f;
  unsigned lo = f2bf(y0) | (f2bf(y1) << 16);
  unsigned hi = f2bf(y2) | (f2bf(y3) << 16);
  *(uint2*)(h1b + (size_t)n * 128 + lane * 2) = make_uint2(lo, hi);
}

// ---------------- K7: MFMA GEMM  [xl2|xr2] = h1(bf16) @ Btp^T ----------------
// A (64 nodes x K256) staged ONCE; loop 4 B-panels of 64 cols each.
__global__ __launch_bounds__(256) void k_gemm2(
    const unsigned* __restrict__ h1b, const unsigned short* __restrict__ Btp,
    unsigned short* __restrict__ xl2b, float* __restrict__ xr2) {
  __shared__ unsigned short Ash[64][264];
  __shared__ unsigned short Bsh[64][264];
  int t = threadIdx.x;
  int bm0 = blockIdx.x * 64;
  int lane = t & 63, w = t >> 6;
  int lm = lane & 15, lk = (lane >> 4) * 8;

  // stage A: 64 rows x 256 bf16 = 2048 uint4
#pragma unroll
  for (int i = 0; i < 8; ++i) {
    int idx = t + 256 * i;
    int row = idx >> 5, c4 = idx & 31;
    int gm = bm0 + row;
    uint4 va = (gm < N_NODES) ? *(const uint4*)(h1b + (size_t)gm * 128 + c4 * 4)
                              : make_uint4(0,0,0,0);
    *(uint4*)(&Ash[row][c4 * 8]) = va;
  }

  for (int pnl = 0; pnl < 4; ++pnl) {
    int n0 = pnl * 64;
#pragma unroll
    for (int i = 0; i < 8; ++i) {
      int idx = t + 256 * i;
      int row = idx >> 5, c4 = idx & 31;
      uint4 vb = *(const uint4*)((const unsigned*)Btp + (size_t)(n0 + row) * 128 + c4 * 4);
      *(uint4*)(&Bsh[row][c4 * 8]) = vb;
    }
    __syncthreads();

    f32x4 acc[4];
#pragma unroll
    for (int i = 0; i < 4; ++i) acc[i] = (f32x4){0.f,0.f,0.f,0.f};
#pragma unroll
    for (int kk = 0; kk < 8; ++kk) {
      bf16x8 a = *(const bf16x8*)(&Ash[16*w + lm][kk*32 + lk]);
#pragma unroll
      for (int tt = 0; tt < 4; ++tt) {
        bf16x8 b = *(const bf16x8*)(&Bsh[16*tt + lm][kk*32 + lk]);
        acc[tt] = __builtin_amdgcn_mfma_f32_16x16x32_bf16(a, b, acc[tt], 0, 0, 0);
      }
    }

#pragma unroll
    for (int tt = 0; tt < 4; ++tt) {
#pragma unroll
      for (int r = 0; r < 4; ++r) {
        int node = bm0 + 16*w + (lane >> 4) * 4 + r;
        if (node < N_NODES) {
          int colg = n0 + tt * 16 + lm;
          float v = acc[tt][r];
          if (colg < 128) xl2b[(size_t)node * 128 + colg] = (unsigned short)f2bf(v);
          else            xr2 [(size_t)node * 128 + (colg - 128)] = v;
        }
      }
    }
    __syncthreads();   // before overwriting Bsh next panel
  }
}

// ---------------- K8: fused GATv2 layer 2 + bias + LN + ELU + pooled atomics ------
// one wave per node; 16 lanes per edge (8 ch/lane), 4 edges/iter, depth-6 pipeline.
__global__ __launch_bounds__(256) void k_gat2(
    const unsigned* __restrict__ xl2b, const float* __restrict__ xr2,
    const float* __restrict__ We, const float* __restrict__ att,
    const float* __restrict__ b2, const float* __restrict__ g2,
    const float* __restrict__ be2,
    const int* __restrict__ off2, const uint2* __restrict__ sent,
    const int* __restrict__ batch,
    float* __restrict__ pool, float* __restrict__ cnt) {
  int tid = threadIdx.x;
  int lane = tid & 63;
  int wv = __builtin_amdgcn_readfirstlane(tid >> 6);
  int row = lane >> 4, col = lane & 15;
  int n = blockIdx.x * 4 + wv;
  int c0 = col * 8;               // 8 channels per lane
  int cu0 = col * 4;              // uint offset into bf16-packed row

  float wev[8], at[8], xr[8];
  *(float4*)(wev)     = *(const float4*)(We + c0);
  *(float4*)(wev + 4) = *(const float4*)(We + c0 + 4);
  *(float4*)(at)      = *(const float4*)(att + c0);
  *(float4*)(at + 4)  = *(const float4*)(att + c0 + 4);
  *(float4*)(xr)      = *(const float4*)(xr2 + (size_t)n * 128 + c0);
  *(float4*)(xr + 4)  = *(const float4*)(xr2 + (size_t)n * 128 + c0 + 4);

  int beg   = __builtin_amdgcn_readfirstlane(off2[n]);
  int quads = __builtin_amdgcn_readfirstlane((off2[n + 1] - beg) >> 2);  // >= 1

  float den = 0.f;
  float ac[8] = {0,0,0,0,0,0,0,0};

  // depth-6 pipeline; each row of 16 lanes owns one edge per quad.
  // named stages (no runtime-indexed arrays -> stays in registers)
  int s0=-1,s1=-1,s2=-1,s3=-1,s4=-1,s5=-1;
  float e0=0,e1=0,e2=0,e3=0,e4=0,e5=0;
  uint4 z = make_uint4(0,0,0,0);
  uint4 u0=z,u1=z,u2=z,u3=z,u4=z,u5=z;
#define LOADSTAGE(S,E,U,Q) { uint2 tt_ = sent[beg + (Q) * 4 + row]; \
    S = (int)tt_.x; E = __uint_as_float(tt_.y); \
    U = *(const uint4*)(xl2b + (size_t)max(S, 0) * 64 + cu0); }
  { LOADSTAGE(s0,e0,u0,0) }
  if (quads > 1) { LOADSTAGE(s1,e1,u1,1) }
  if (quads > 2) { LOADSTAGE(s2,e2,u2,2) }
  if (quads > 3) { LOADSTAGE(s3,e3,u3,3) }
  if (quads > 4) { LOADSTAGE(s4,e4,u4,4) }
  if (quads > 5) { LOADSTAGE(s5,e5,u5,5) }

  for (int q = 0; q < quads; ++q) {
    int cs = s0; float ce = e0; uint4 cu = u0;
    s0=s1; e0=e1; u0=u1;
    s1=s2; e1=e2; u1=u2;
    s2=s3; e2=e3; u2=u3;
    s3=s4; e3=e4; u3=u4;
    s4=s5; e4=e5; u4=u5;
    if (q + 6 < quads) { LOADSTAGE(s5,e5,u5,q+6) }
    float v[8];
    v[0]=bflo(cu.x); v[1]=bfhi(cu.x); v[2]=bflo(cu.y); v[3]=bfhi(cu.y);
    v[4]=bflo(cu.z); v[5]=bfhi(cu.z); v[6]=bflo(cu.w); v[7]=bfhi(cu.w);
    float p = 0.f;
#pragma unroll
    for (int j = 0; j < 8; ++j) {
      float m = v[j] + fmaf(ce, wev[j], xr[j]);
      m = fmaxf(m, 0.2f * m);
      p = fmaf(m, at[j], p);
    }
    p = red16d(p);
    float w = (cs >= 0) ? __expf(p) : 0.f;
    den += w;
#pragma unroll
    for (int j = 0; j < 8; ++j) ac[j] = fmaf(w, v[j], ac[j]);
  }
#undef LOADSTAGE
  den += __shfl_xor(den, 16); den += __shfl_xor(den, 32);
#pragma unroll
  for (int j = 0; j < 8; ++j) {
    ac[j] += __shfl_xor(ac[j], 16);
    ac[j] += __shfl_xor(ac[j], 32);
  }

  float inv = 1.0f / (den + 1e-16f);
  float o[8], y[8];
  float bv[8], gv[8], bev[8];
  *(float4*)(bv)      = *(const float4*)(b2 + c0);
  *(float4*)(bv + 4)  = *(const float4*)(b2 + c0 + 4);
  *(float4*)(gv)      = *(const float4*)(g2 + c0);
  *(float4*)(gv + 4)  = *(const float4*)(g2 + c0 + 4);
  *(float4*)(bev)     = *(const float4*)(be2 + c0);
  *(float4*)(bev + 4) = *(const float4*)(be2 + c0 + 4);
  float osum = 0.f;
#pragma unroll
  for (int j = 0; j < 8; ++j) { o[j] = ac[j] * inv + bv[j]; osum += o[j]; }
  float mu = red64(osum) * (1.0f / 512.0f);
  float vsum = 0.f;
#pragma unroll
  for (int j = 0; j < 8; ++j) { o[j] -= mu; vsum += o[j] * o[j]; }
  float rstd = rsqrtf(red64(vsum) * (1.0f / 512.0f) + LN_EPS);
#pragma unroll
  for (int j = 0; j < 8; ++j) {
    float t2 = o[j] * rstd * gv[j] + bev[j];
    y[j] = t2 > 0.f ? t2 : __expf(t2) - 1.0f;
  }

  // block-level pool dedup (batch sorted -> usually 1 graph per block)
  __shared__ float pbuf[4][128];
  __shared__ int gbuf[4];
  if (row == 0) {
#pragma unroll
    for (int j = 0; j < 8; ++j) pbuf[wv][c0 + j] = y[j];
  }
  if (lane == 0) gbuf[wv] = batch[n];
  __syncthreads();
  if (wv == 0) {
    int r = blockIdx.x & (NREP - 1);
    int ch = lane;                       // handles ch and ch+64
    float acc0 = pbuf[0][ch], acc1 = pbuf[0][ch+64];
    int cg = gbuf[0], cn = 1;
#pragma unroll
    for (int i = 1; i < 4; ++i) {
      if (gbuf[i] == cg) { acc0 += pbuf[i][ch]; acc1 += pbuf[i][ch+64]; cn++; }
      else {
        float* pp = pool + ((size_t)(r * N_GRAPHS + cg)) * 128;
        atomicAdd(pp + ch, acc0); atomicAdd(pp + ch + 64, acc1);
        if (lane == 0) atomicAdd(&cnt[r * N_GRAPHS + cg], (float)cn);
        cg = gbuf[i]; acc0 = pbuf[i][ch]; acc1 = pbuf[i][ch+64]; cn = 1;
      }
    }
    float* pp = pool + ((size_t)(r * N_GRAPHS + cg)) * 128;
    atomicAdd(pp + ch, acc0); atomicAdd(pp + ch + 64, acc1);
    if (lane == 0) atomicAdd(&cnt[r * N_GRAPHS + cg], (float)cn);
  }
}

// ---------------- K9: reduce replicas, divide by count ----------------
__global__ void k_final(const float* __restrict__ pool, const float* __restrict__ cnt,
                        float* __restrict__ out) {
  int idx = blockIdx.x * 256 + threadIdx.x;
  if (idx >= N_GRAPHS * 128) return;
  int g = idx >> 7, c = idx & 127;
  float s = 0.f, nn = 0.f;
#pragma unroll
  for (int r = 0; r < NREP; ++r) {
    s  += pool[((size_t)(r * N_GRAPHS + g)) * 128 + c];
    nn += cnt[r * N_GRAPHS + g];
  }
  out[idx] = s / fmaxf(nn, 1.0f);
}

// ---------------- launch ----------------
extern "C" void kernel_launch(void* const* d_in, const int* in_sizes, int n_in,
                              void* d_out, int out_size, void* d_ws, size_t ws_size,
                              hipStream_t stream) {
  const float* x    = (const float*)d_in[0];
  const int*   ei   = (const int*)  d_in[1];
  const float* ea   = (const float*)d_in[2];
  const int*   batch= (const int*)  d_in[3];
  const float* Wl1  = (const float*)d_in[4];
  const float* Wr1  = (const float*)d_in[5];
  const float* We1  = (const float*)d_in[6];
  const float* att1 = (const float*)d_in[7];
  const float* b1   = (const float*)d_in[8];
  const float* g1   = (const float*)d_in[9];
  const float* be1  = (const float*)d_in[10];
  const float* Wl2  = (const float*)d_in[11];
  const float* Wr2  = (const float*)d_in[12];
  const float* We2  = (const float*)d_in[13];
  const float* att2 = (const float*)d_in[14];
  const float* b2   = (const float*)d_in[15];
  const float* g2   = (const float*)d_in[16];
  const float* be2  = (const float*)d_in[17];
  const int* srcp = ei;
  const int* dstp = ei + N_EDGES;

  const int MAXE2 = N_EDGES + 4 * N_NODES;

  char* ws = (char*)d_ws;
  size_t off = 0;
  auto alloc = [&](size_t bytes) {
    char* p = ws + off; off += (bytes + 15) & ~(size_t)15; return p;
  };
  // --- zeroed region start ---
  int*            deg   = (int*)           alloc((size_t)N_NODES * 4);
  float*          easum = (float*)         alloc((size_t)N_NODES * 4);
  // --- zeroed region end ---
  int*            off2  = (int*)           alloc((size_t)(N_NODES + 1) * 4);
  int*            part  = (int*)           alloc((size_t)256 * 4);
  int*            base  = (int*)           alloc((size_t)257 * 4);
  int*            erank = (int*)           alloc((size_t)N_EDGES * 4);
  uint2*          sent  = (uint2*)         alloc((size_t)MAXE2 * 8);
  uint4*          xh16  = (uint4*)         alloc((size_t)N_NODES * 16);
  unsigned*       Wlh   = (unsigned*)      alloc((size_t)4 * 256 * 4);
  unsigned*       h1b   = (unsigned*)      alloc((size_t)N_NODES * 128 * 4);  // bf16 256ch
  unsigned short* xl2b  = (unsigned short*)alloc((size_t)N_NODES * 128 * 2);  // bf16 128ch
  float*          xr2   = (float*)         alloc((size_t)N_NODES * 128 * 4);
  unsigned short* Btp   = (unsigned short*)alloc((size_t)256 * 256 * 2);
  float*          pool  = (float*)         alloc((size_t)NREP * N_GRAPHS * 128 * 4);
  float*          cnt   = (float*)         alloc((size_t)NREP * N_GRAPHS * 4);

  (void)hipMemsetAsync(deg, 0, (char*)off2 - (char*)deg, stream);  // deg, easum
  (void)hipMemsetAsync(pool, 0, ((char*)cnt + (((size_t)NREP*N_GRAPHS*4 + 15) & ~(size_t)15))
                           - (char*)pool, stream);

  k_hist    <<<N_EDGES / 256, 256, 0, stream>>>(dstp, ea, deg, easum, erank);
  k_prep    <<<SCAN_BLKS + 4 + 256, 256, 0, stream>>>(x, xh16, Wl1, Wlh, Wl2, Wr2, Btp);
  k_scanA   <<<SCAN_BLKS, 256, 0, stream>>>(deg, part);
  k_scanB   <<<1, 256, 0, stream>>>(part, base);
  k_scanC   <<<SCAN_BLKS, 256, 0, stream>>>(deg, base, easum, off2, sent);
  k_scatter <<<N_EDGES / 256, 256, 0, stream>>>(srcp, dstp, ea, off2, erank, sent);
  k_gat1    <<<N_NODES / 4, 256, 0, stream>>>(x, xh16, Wlh, Wr1, We1, att1, b1, g1, be1,
                                              off2, sent, h1b);
  k_gemm2   <<<(N_NODES + 63) / 64, 256, 0, stream>>>(h1b, Btp, xl2b, xr2);
  k_gat2    <<<N_NODES / 4, 256, 0, stream>>>((const unsigned*)xl2b, xr2, We2, att2,
                                              b2, g2, be2,
                                              off2, sent, batch, pool, cnt);
  k_final   <<<(N_GRAPHS * 128) / 256, 256, 0, stream>>>(pool, cnt, (float*)d_out);
}